// Round 6
// baseline (479.544 us; speedup 1.0000x reference)
//
#include <hip/hip_runtime.h>
#include <hip/hip_bf16.h>
#include <math.h>

#define N_NODES 50000
#define N_EDGES 1600000
#define N_GRAPHS 64
#define N_PART 8
#define NB 391             // dst buckets of 128 nodes: b = dst >> 7
#define CAP_BP 768         // per-(bucket,partition) capacity; mean 512, sd ~22 -> 11 sigma
#define ROW_STRIDE 80      // per-node adjacency capacity; Poisson(32) > 80: P~5e-13

// ---------------------------------------------------------------------------
// DPP cross-lane add helpers (VALU pipe, no LDS).
// ---------------------------------------------------------------------------
template <int CTRL>
__device__ __forceinline__ float dpp_add(float v) {
    int r = __builtin_amdgcn_update_dpp(0, __builtin_bit_cast(int, v), CTRL, 0xF, 0xF, true);
    return v + __builtin_bit_cast(float, r);
}

__device__ __forceinline__ float red16(float v) {
    v = dpp_add<0xB1>(v);    // quad_perm [1,0,3,2]
    v = dpp_add<0x4E>(v);    // quad_perm [2,3,0,1]
    v = dpp_add<0x141>(v);   // row_half_mirror
    v = dpp_add<0x140>(v);   // row_mirror
    return v;
}

__device__ __forceinline__ float edge_ev_l1(float xlv, float xrn, float attv) {
    float u = xlv + xrn;
    u = u > 0.f ? u : 0.2f * u;
    float v = red16(attv * u);
    v += __shfl_xor(v, 16);
    return __expf(v);
}

__device__ __forceinline__ float edge_ev_l2(float xlv, float xrn, float attv) {
    float u = xlv + xrn;
    u = u > 0.f ? u : 0.2f * u;
    float v = red16(attv * u);
    v += __shfl_xor(v, 16);
    v += __shfl_xor(v, 32);
    return __expf(v);
}

// ---------------------------------------------------------------------------
// Register-tiled dense transform: out = x @ [Wl | Wr].
// ---------------------------------------------------------------------------
template <int K>
__global__ __launch_bounds__(256) void gemm_tiled(
    const float* __restrict__ x, const float* __restrict__ Wl,
    const float* __restrict__ Wr, float* __restrict__ xl, float* __restrict__ xr) {
    __shared__ float xs[64][K + 1];
    const int t = threadIdx.x;
    const int base = blockIdx.x * 64;
    const int nf4 = 64 * K / 4;
    for (int f = t; f < nf4; f += 256) {
        const int row = f / (K / 4);
        const int c4 = f % (K / 4);
        float4 v = make_float4(0.f, 0.f, 0.f, 0.f);
        if (base + row < N_NODES)
            v = *(const float4*)(x + (size_t)(base + row) * K + c4 * 4);
        xs[row][c4 * 4 + 0] = v.x;
        xs[row][c4 * 4 + 1] = v.y;
        xs[row][c4 * 4 + 2] = v.z;
        xs[row][c4 * 4 + 3] = v.w;
    }
    __syncthreads();
    const int lane = t & 63;
    const int w = __builtin_amdgcn_readfirstlane(t >> 6);
    const float* __restrict__ W = (w < 2) ? Wl : Wr;
    const int cb = (w & 1) * 32;
    float acc[32];
#pragma unroll
    for (int j = 0; j < 32; ++j) acc[j] = 0.f;
#pragma unroll 2
    for (int k = 0; k < K; ++k) {
        const float xv = xs[lane][k];
        const float* __restrict__ Wrow = W + k * 64 + cb;
#pragma unroll
        for (int j = 0; j < 32; ++j) acc[j] = fmaf(xv, Wrow[j], acc[j]);
    }
    const int n = base + lane;
    if (n < N_NODES) {
        float* __restrict__ o = (w < 2) ? xl : xr;
#pragma unroll
        for (int j = 0; j < 32; j += 4) {
            float4 v = {acc[j], acc[j + 1], acc[j + 2], acc[j + 3]};
            *(float4*)(o + (size_t)n * 64 + cb + j) = v;
        }
    }
}

// ---------------------------------------------------------------------------
// Stage 1: bin edges by coarse dst bucket (128 nodes/bucket), partitioned by
// blockIdx&7. Each (bucket,partition) cell receives ~512 consecutive appends
// -> lines fill 16/16 (dense writes, unlike R5's 4-per-128B cells).
// Payload packed: (src << 7) | (dst & 127).
// ---------------------------------------------------------------------------
__global__ __launch_bounds__(256) void bin_kernel(
    const int* __restrict__ ei, int* __restrict__ cur, int* __restrict__ seg) {
    const int e = blockIdx.x * 256 + threadIdx.x;
    if (e >= N_EDGES) return;
    const int p = blockIdx.x & (N_PART - 1);
    const int s = ei[e];
    const int d = ei[N_EDGES + e];
    const int cell = (d >> 7) * N_PART + p;
    const int pos = atomicAdd(&cur[cell], 1);
    if (pos < CAP_BP) seg[cell * CAP_BP + pos] = (s << 7) | (d & 127);
}

// Stage 2: one block per bucket expands packed entries into stride-80 rows
// using LDS per-node counters; emits deg. Each bucket's 40 KB rows window is
// written by exactly one block (single-owner -> lines flush once).
__global__ __launch_bounds__(256) void expand_kernel(
    const int* __restrict__ cur, const int* __restrict__ seg,
    int* __restrict__ deg, int* __restrict__ rows) {
    __shared__ int ldeg[128];
    const int b = blockIdx.x;
    const int t = threadIdx.x;
    if (t < 128) ldeg[t] = 0;
    __syncthreads();
    const int node_base = b * 128;
#pragma unroll
    for (int p = 0; p < N_PART; ++p) {
        const int cell = b * N_PART + p;
        int c = cur[cell];
        c = c < CAP_BP ? c : CAP_BP;
        const int base = cell * CAP_BP;
        for (int i = t; i < c; i += 256) {
            const int en = seg[base + i];
            const int ld = en & 127;
            const int pos = atomicAdd(&ldeg[ld], 1);
            if (pos < ROW_STRIDE) rows[(node_base + ld) * ROW_STRIDE + pos] = en >> 7;
        }
    }
    __syncthreads();
    if (t < 128) {
        const int n = node_base + t;
        if (n < N_NODES) {
            int c = ldeg[t];
            deg[n] = c < ROW_STRIDE ? c : ROW_STRIDE;
        }
    }
}

// ---------------------------------------------------------------------------
// Node-centric GATv2 layer: one wave per dst node, x4 unrolled ILP chains.
// ---------------------------------------------------------------------------
__global__ __launch_bounds__(256) void node_l1(
    const int* __restrict__ deg, const int* __restrict__ rows,
    const float* __restrict__ xl, const float* __restrict__ xr,
    const float* __restrict__ att, const float* __restrict__ b1,
    float* __restrict__ h1) {
    const int n = (blockIdx.x * 256 + threadIdx.x) >> 6;
    const int lane = threadIdx.x & 63;
    const float xrn = xr[n * 64 + lane];
    const float xln = xl[n * 64 + lane];
    const float attv = att[lane];
    float ev = edge_ev_l1(xln, xrn, attv);   // self loop
    float accv = ev * xln;
    float ssum = ev;
    const int cnt = __builtin_amdgcn_readfirstlane(deg[n]);
    const int* __restrict__ row = rows + n * ROW_STRIDE;
    int i = 0;
    for (; i + 3 < cnt; i += 4) {
        const int s0 = row[i + 0];
        const int s1 = row[i + 1];
        const int s2 = row[i + 2];
        const int s3 = row[i + 3];
        const float a0 = xl[s0 * 64 + lane];
        const float a1 = xl[s1 * 64 + lane];
        const float a2 = xl[s2 * 64 + lane];
        const float a3 = xl[s3 * 64 + lane];
        const float e0 = edge_ev_l1(a0, xrn, attv);
        const float e1 = edge_ev_l1(a1, xrn, attv);
        const float e2 = edge_ev_l1(a2, xrn, attv);
        const float e3 = edge_ev_l1(a3, xrn, attv);
        accv = fmaf(e0, a0, accv);
        accv = fmaf(e1, a1, accv);
        accv = fmaf(e2, a2, accv);
        accv = fmaf(e3, a3, accv);
        ssum += (e0 + e1) + (e2 + e3);
    }
    for (; i < cnt; ++i) {
        const int src = row[i];
        const float xlv = xl[src * 64 + lane];
        const float e2 = edge_ev_l1(xlv, xrn, attv);
        accv = fmaf(e2, xlv, accv);
        ssum += e2;
    }
    float o = accv / (ssum + 1e-16f) + b1[lane];
    h1[n * 64 + lane] = o > 0.f ? o : expm1f(o);
}

__global__ __launch_bounds__(256) void node_l2(
    const int* __restrict__ deg, const int* __restrict__ rows,
    const float* __restrict__ xl, const float* __restrict__ xr,
    const float* __restrict__ att, const float* __restrict__ b2,
    float* __restrict__ h2) {
    const int n = (blockIdx.x * 256 + threadIdx.x) >> 6;
    const int lane = threadIdx.x & 63;
    const float xrn = xr[n * 64 + lane];
    const float xln = xl[n * 64 + lane];
    const float attv = att[lane];
    float ev = edge_ev_l2(xln, xrn, attv);
    float accv = ev * xln;
    float ssum = ev;
    const int cnt = __builtin_amdgcn_readfirstlane(deg[n]);
    const int* __restrict__ row = rows + n * ROW_STRIDE;
    int i = 0;
    for (; i + 3 < cnt; i += 4) {
        const int s0 = row[i + 0];
        const int s1 = row[i + 1];
        const int s2 = row[i + 2];
        const int s3 = row[i + 3];
        const float a0 = xl[s0 * 64 + lane];
        const float a1 = xl[s1 * 64 + lane];
        const float a2 = xl[s2 * 64 + lane];
        const float a3 = xl[s3 * 64 + lane];
        const float e0 = edge_ev_l2(a0, xrn, attv);
        const float e1 = edge_ev_l2(a1, xrn, attv);
        const float e2 = edge_ev_l2(a2, xrn, attv);
        const float e3 = edge_ev_l2(a3, xrn, attv);
        accv = fmaf(e0, a0, accv);
        accv = fmaf(e1, a1, accv);
        accv = fmaf(e2, a2, accv);
        accv = fmaf(e3, a3, accv);
        ssum += (e0 + e1) + (e2 + e3);
    }
    for (; i < cnt; ++i) {
        const int src = row[i];
        const float xlv = xl[src * 64 + lane];
        const float e2 = edge_ev_l2(xlv, xrn, attv);
        accv = fmaf(e2, xlv, accv);
        ssum += e2;
    }
    float o = accv / (ssum + 1e-16f) + b2[lane];
    h2[n * 64 + lane] = o > 0.f ? o : expm1f(o);
}

// Mean-pool accumulation over sorted batch ids.
__global__ __launch_bounds__(64) void pool_kernel(
    const float* __restrict__ h2, const int* __restrict__ batch,
    float* __restrict__ pooled, float* __restrict__ cnt) {
    const int t = threadIdx.x;
    const int base = blockIdx.x * 64;
    float local = 0.f, lc = 0.f;
    int cur = -1;
    for (int j = 0; j < 64; ++j) {
        const int n = base + j;
        if (n >= N_NODES) break;
        const int g = batch[n];
        if (g != cur) {
            if (cur >= 0) {
                unsafeAtomicAdd(&pooled[cur * 64 + t], local);
                if (t == 0) unsafeAtomicAdd(&cnt[cur], lc);
            }
            cur = g; local = 0.f; lc = 0.f;
        }
        local += h2[n * 64 + t];
        lc += 1.f;
    }
    if (cur >= 0) {
        unsafeAtomicAdd(&pooled[cur * 64 + t], local);
        if (t == 0) unsafeAtomicAdd(&cnt[cur], lc);
    }
}

__global__ __launch_bounds__(128) void head_kernel(
    const float* __restrict__ pooled, const float* __restrict__ cnt,
    const float* __restrict__ lin_w, const float* __restrict__ lin_b,
    float* __restrict__ out) {
    const int i = threadIdx.x;          // 0..127 -> (g, k)
    const int g = i >> 1, k = i & 1;
    float c = cnt[g];
    c = c > 1.f ? c : 1.f;
    float a = 0.f;
#pragma unroll
    for (int j = 0; j < 64; ++j) a = fmaf(pooled[g * 64 + j] / c, lin_w[j * 2 + k], a);
    out[i] = a + lin_b[k];
}

extern "C" void kernel_launch(void* const* d_in, const int* in_sizes, int n_in,
                              void* d_out, int out_size, void* d_ws, size_t ws_size,
                              hipStream_t stream) {
    const float* x     = (const float*)d_in[0];
    const int*   ei    = (const int*)d_in[1];
    const int*   batch = (const int*)d_in[2];
    const float* Wl1   = (const float*)d_in[3];
    const float* Wr1   = (const float*)d_in[4];
    const float* att1  = (const float*)d_in[5];
    const float* b1    = (const float*)d_in[6];
    const float* Wl2   = (const float*)d_in[7];
    const float* Wr2   = (const float*)d_in[8];
    const float* att2  = (const float*)d_in[9];
    const float* b2    = (const float*)d_in[10];
    const float* lin_w = (const float*)d_in[11];
    const float* lin_b = (const float*)d_in[12];

    float* ws = (float*)d_ws;
    float* xl     = ws;                          //  3,200,000
    float* xr     = ws + 3200000;                //  3,200,000
    float* h1     = ws + 6400000;                //  3,200,000 (reused as h2)
    int*   rows   = (int*)(ws + 9600000);        //  4,003,840 (50048*80)
    int*   deg    = (int*)(ws + 13603840);       //     50,048
    int*   cur    = (int*)(ws + 13653888);       //      3,128 (391*8) -- memset start
    float* pooled = ws + 13657016;               //      4,096
    float* cnt    = ws + 13661112;               //         64
    int*   seg    = (int*)(ws + 13661176);       //  2,402,304 (391*8*768)
    // total ~16.06M floats ~= 64.3 MB (ws is 256 MiB)

    // zero cur + pooled + cnt (contiguous)
    hipMemsetAsync(cur, 0, (size_t)(3128 + 4096 + 64) * sizeof(float), stream);

    // ---- adjacency build: dense bucket binning, then per-bucket expand ----
    bin_kernel<<<(N_EDGES + 255) / 256, 256, 0, stream>>>(ei, cur, seg);
    expand_kernel<<<NB, 256, 0, stream>>>(cur, seg, deg, rows);

    const int gblocks = (N_NODES + 63) / 64;   // 782

    // ---- layer 1 ----
    gemm_tiled<128><<<gblocks, 256, 0, stream>>>(x, Wl1, Wr1, xl, xr);
    node_l1<<<N_NODES / 4, 256, 0, stream>>>(deg, rows, xl, xr, att1, b1, h1);

    // ---- layer 2 (h2 reuses h1 buffer; gemm consumed h1 first) ----
    gemm_tiled<64><<<gblocks, 256, 0, stream>>>(h1, Wl2, Wr2, xl, xr);
    node_l2<<<N_NODES / 4, 256, 0, stream>>>(deg, rows, xl, xr, att2, b2, h1);

    // ---- pool + head ----
    pool_kernel<<<(N_NODES + 63) / 64, 64, 0, stream>>>(h1, batch, pooled, cnt);
    head_kernel<<<1, 128, 0, stream>>>(pooled, cnt, lin_w, lin_b, (float*)d_out);
}

// Round 7
// 360.888 us; speedup vs baseline: 1.3288x; 1.3288x over previous
//
#include <hip/hip_runtime.h>
#include <hip/hip_bf16.h>
#include <math.h>

#define N_NODES 50000
#define N_EDGES 1600000
#define N_GRAPHS 64
#define NB 391             // dst buckets of 128 nodes: b = dst >> 7
#define NBLK 256           // partition blocks
#define CHUNK 6250         // edges per partition block (256*6250 = 1.6M exactly)
#define ROW_STRIDE 80      // per-node adjacency capacity; Poisson(32) > 80: P~5e-13

// ---------------------------------------------------------------------------
// DPP cross-lane add helpers (VALU pipe, no LDS).
// ---------------------------------------------------------------------------
template <int CTRL>
__device__ __forceinline__ float dpp_add(float v) {
    int r = __builtin_amdgcn_update_dpp(0, __builtin_bit_cast(int, v), CTRL, 0xF, 0xF, true);
    return v + __builtin_bit_cast(float, r);
}

__device__ __forceinline__ float red16(float v) {
    v = dpp_add<0xB1>(v);    // quad_perm [1,0,3,2]
    v = dpp_add<0x4E>(v);    // quad_perm [2,3,0,1]
    v = dpp_add<0x141>(v);   // row_half_mirror
    v = dpp_add<0x140>(v);   // row_mirror
    return v;
}

__device__ __forceinline__ float edge_ev_l1(float xlv, float xrn, float attv) {
    float u = xlv + xrn;
    u = u > 0.f ? u : 0.2f * u;
    float v = red16(attv * u);
    v += __shfl_xor(v, 16);
    return __expf(v);
}

__device__ __forceinline__ float edge_ev_l2(float xlv, float xrn, float attv) {
    float u = xlv + xrn;
    u = u > 0.f ? u : 0.2f * u;
    float v = red16(attv * u);
    v += __shfl_xor(v, 16);
    v += __shfl_xor(v, 32);
    return __expf(v);
}

// ---------------------------------------------------------------------------
// Register-tiled dense transform: out = x @ [Wl | Wr].
// ---------------------------------------------------------------------------
template <int K>
__global__ __launch_bounds__(256) void gemm_tiled(
    const float* __restrict__ x, const float* __restrict__ Wl,
    const float* __restrict__ Wr, float* __restrict__ xl, float* __restrict__ xr) {
    __shared__ float xs[64][K + 1];
    const int t = threadIdx.x;
    const int base = blockIdx.x * 64;
    const int nf4 = 64 * K / 4;
    for (int f = t; f < nf4; f += 256) {
        const int row = f / (K / 4);
        const int c4 = f % (K / 4);
        float4 v = make_float4(0.f, 0.f, 0.f, 0.f);
        if (base + row < N_NODES)
            v = *(const float4*)(x + (size_t)(base + row) * K + c4 * 4);
        xs[row][c4 * 4 + 0] = v.x;
        xs[row][c4 * 4 + 1] = v.y;
        xs[row][c4 * 4 + 2] = v.z;
        xs[row][c4 * 4 + 3] = v.w;
    }
    __syncthreads();
    const int lane = t & 63;
    const int w = __builtin_amdgcn_readfirstlane(t >> 6);
    const float* __restrict__ W = (w < 2) ? Wl : Wr;
    const int cb = (w & 1) * 32;
    float acc[32];
#pragma unroll
    for (int j = 0; j < 32; ++j) acc[j] = 0.f;
#pragma unroll 2
    for (int k = 0; k < K; ++k) {
        const float xv = xs[lane][k];
        const float* __restrict__ Wrow = W + k * 64 + cb;
#pragma unroll
        for (int j = 0; j < 32; ++j) acc[j] = fmaf(xv, Wrow[j], acc[j]);
    }
    const int n = base + lane;
    if (n < N_NODES) {
        float* __restrict__ o = (w < 2) ? xl : xr;
#pragma unroll
        for (int j = 0; j < 32; j += 4) {
            float4 v = {acc[j], acc[j + 1], acc[j + 2], acc[j + 3]};
            *(float4*)(o + (size_t)n * 64 + cb + j) = v;
        }
    }
}

// ---------------------------------------------------------------------------
// Atomic-free radix partition of edges by dst bucket (d>>7).
// Pass A: per-block LDS histogram -> countsRM[block][bucket] (coalesced).
// ---------------------------------------------------------------------------
__global__ __launch_bounds__(256) void count_kernel(
    const int* __restrict__ ei, int* __restrict__ countsRM) {
    __shared__ int h[NB];
    const int t = threadIdx.x;
    for (int k = t; k < NB; k += 256) h[k] = 0;
    __syncthreads();
    const int base = blockIdx.x * CHUNK;
    for (int e = base + t; e < base + CHUNK; e += 256)
        atomicAdd(&h[ei[N_EDGES + e] >> 7], 1);
    __syncthreads();
    for (int k = t; k < NB; k += 256) countsRM[blockIdx.x * NB + k] = h[k];
}

// Pass B1: one block per bucket: exclusive scan over the 256 block counts.
// scanT[bucket*256 + blk] = edges of this bucket from blocks < blk.
__global__ __launch_bounds__(256) void scan_bucket(
    const int* __restrict__ countsRM, int* __restrict__ scanT,
    int* __restrict__ totals) {
    __shared__ int tmp[256];
    const int b = blockIdx.x;
    const int t = threadIdx.x;
    const int v0 = countsRM[t * NB + b];
    tmp[t] = v0;
    __syncthreads();
    for (int off = 1; off < 256; off <<= 1) {
        int v = (t >= off) ? tmp[t - off] : 0;
        __syncthreads();
        tmp[t] += v;
        __syncthreads();
    }
    scanT[b * 256 + t] = tmp[t] - v0;   // exclusive
    if (t == 255) totals[b] = tmp[t];
}

// Pass B2: exclusive scan of the 391 bucket totals -> bucketBase[0..391].
__global__ __launch_bounds__(512) void scan_total(
    const int* __restrict__ totals, int* __restrict__ bucketBase) {
    __shared__ int tmp[512];
    const int t = threadIdx.x;
    const int v0 = (t < NB) ? totals[t] : 0;
    tmp[t] = v0;
    __syncthreads();
    for (int off = 1; off < 512; off <<= 1) {
        int v = (t >= off) ? tmp[t - off] : 0;
        __syncthreads();
        tmp[t] += v;
        __syncthreads();
    }
    if (t < NB) bucketBase[t] = tmp[t] - v0;
    if (t == NB - 1) bucketBase[NB] = tmp[t];
}

// Pass C: scatter into bucket-grouped array. LDS cursors preloaded with this
// block's exclusive offsets -> each block writes dense private runs (~16
// consecutive entries = one 64B line per bucket). Zero global atomics.
// Payload packed: (src << 7) | (dst & 127).
__global__ __launch_bounds__(256) void scatter2_kernel(
    const int* __restrict__ ei, const int* __restrict__ scanT,
    const int* __restrict__ bucketBase, int* __restrict__ sortedE) {
    __shared__ int cursor[NB];
    const int t = threadIdx.x;
    const int b = blockIdx.x;
    for (int k = t; k < NB; k += 256)
        cursor[k] = bucketBase[k] + scanT[k * 256 + b];
    __syncthreads();
    const int base = b * CHUNK;
    for (int e = base + t; e < base + CHUNK; e += 256) {
        const int s = ei[e];
        const int d = ei[N_EDGES + e];
        const int idx = atomicAdd(&cursor[d >> 7], 1);   // LDS atomic
        sortedE[idx] = (s << 7) | (d & 127);
    }
}

// Expand: one block per bucket reads its dense range and groups per node into
// stride-80 rows via LDS counters; emits deg. Single-owner 40KB rows window.
__global__ __launch_bounds__(256) void expand_kernel(
    const int* __restrict__ bucketBase, const int* __restrict__ sortedE,
    int* __restrict__ deg, int* __restrict__ rows) {
    __shared__ int ldeg[128];
    const int b = blockIdx.x;
    const int t = threadIdx.x;
    if (t < 128) ldeg[t] = 0;
    __syncthreads();
    const int beg = bucketBase[b];
    const int end = bucketBase[b + 1];
    const int node_base = b * 128;
    for (int i = beg + t; i < end; i += 256) {
        const int en = sortedE[i];
        const int ld = en & 127;
        const int pos = atomicAdd(&ldeg[ld], 1);
        if (pos < ROW_STRIDE) rows[(node_base + ld) * ROW_STRIDE + pos] = en >> 7;
    }
    __syncthreads();
    if (t < 128) {
        const int n = node_base + t;
        if (n < N_NODES) {
            int c = ldeg[t];
            deg[n] = c < ROW_STRIDE ? c : ROW_STRIDE;
        }
    }
}

// ---------------------------------------------------------------------------
// Node-centric GATv2 layer: one wave per dst node, x4 unrolled ILP chains.
// ---------------------------------------------------------------------------
__global__ __launch_bounds__(256) void node_l1(
    const int* __restrict__ deg, const int* __restrict__ rows,
    const float* __restrict__ xl, const float* __restrict__ xr,
    const float* __restrict__ att, const float* __restrict__ b1,
    float* __restrict__ h1) {
    const int n = (blockIdx.x * 256 + threadIdx.x) >> 6;
    const int lane = threadIdx.x & 63;
    const float xrn = xr[n * 64 + lane];
    const float xln = xl[n * 64 + lane];
    const float attv = att[lane];
    float ev = edge_ev_l1(xln, xrn, attv);   // self loop
    float accv = ev * xln;
    float ssum = ev;
    const int cnt = __builtin_amdgcn_readfirstlane(deg[n]);
    const int* __restrict__ row = rows + n * ROW_STRIDE;
    int i = 0;
    for (; i + 3 < cnt; i += 4) {
        const int s0 = row[i + 0];
        const int s1 = row[i + 1];
        const int s2 = row[i + 2];
        const int s3 = row[i + 3];
        const float a0 = xl[s0 * 64 + lane];
        const float a1 = xl[s1 * 64 + lane];
        const float a2 = xl[s2 * 64 + lane];
        const float a3 = xl[s3 * 64 + lane];
        const float e0 = edge_ev_l1(a0, xrn, attv);
        const float e1 = edge_ev_l1(a1, xrn, attv);
        const float e2 = edge_ev_l1(a2, xrn, attv);
        const float e3 = edge_ev_l1(a3, xrn, attv);
        accv = fmaf(e0, a0, accv);
        accv = fmaf(e1, a1, accv);
        accv = fmaf(e2, a2, accv);
        accv = fmaf(e3, a3, accv);
        ssum += (e0 + e1) + (e2 + e3);
    }
    for (; i < cnt; ++i) {
        const int src = row[i];
        const float xlv = xl[src * 64 + lane];
        const float e2 = edge_ev_l1(xlv, xrn, attv);
        accv = fmaf(e2, xlv, accv);
        ssum += e2;
    }
    float o = accv / (ssum + 1e-16f) + b1[lane];
    h1[n * 64 + lane] = o > 0.f ? o : expm1f(o);
}

__global__ __launch_bounds__(256) void node_l2(
    const int* __restrict__ deg, const int* __restrict__ rows,
    const float* __restrict__ xl, const float* __restrict__ xr,
    const float* __restrict__ att, const float* __restrict__ b2,
    float* __restrict__ h2) {
    const int n = (blockIdx.x * 256 + threadIdx.x) >> 6;
    const int lane = threadIdx.x & 63;
    const float xrn = xr[n * 64 + lane];
    const float xln = xl[n * 64 + lane];
    const float attv = att[lane];
    float ev = edge_ev_l2(xln, xrn, attv);
    float accv = ev * xln;
    float ssum = ev;
    const int cnt = __builtin_amdgcn_readfirstlane(deg[n]);
    const int* __restrict__ row = rows + n * ROW_STRIDE;
    int i = 0;
    for (; i + 3 < cnt; i += 4) {
        const int s0 = row[i + 0];
        const int s1 = row[i + 1];
        const int s2 = row[i + 2];
        const int s3 = row[i + 3];
        const float a0 = xl[s0 * 64 + lane];
        const float a1 = xl[s1 * 64 + lane];
        const float a2 = xl[s2 * 64 + lane];
        const float a3 = xl[s3 * 64 + lane];
        const float e0 = edge_ev_l2(a0, xrn, attv);
        const float e1 = edge_ev_l2(a1, xrn, attv);
        const float e2 = edge_ev_l2(a2, xrn, attv);
        const float e3 = edge_ev_l2(a3, xrn, attv);
        accv = fmaf(e0, a0, accv);
        accv = fmaf(e1, a1, accv);
        accv = fmaf(e2, a2, accv);
        accv = fmaf(e3, a3, accv);
        ssum += (e0 + e1) + (e2 + e3);
    }
    for (; i < cnt; ++i) {
        const int src = row[i];
        const float xlv = xl[src * 64 + lane];
        const float e2 = edge_ev_l2(xlv, xrn, attv);
        accv = fmaf(e2, xlv, accv);
        ssum += e2;
    }
    float o = accv / (ssum + 1e-16f) + b2[lane];
    h2[n * 64 + lane] = o > 0.f ? o : expm1f(o);
}

// Mean-pool accumulation over sorted batch ids.
__global__ __launch_bounds__(64) void pool_kernel(
    const float* __restrict__ h2, const int* __restrict__ batch,
    float* __restrict__ pooled, float* __restrict__ cnt) {
    const int t = threadIdx.x;
    const int base = blockIdx.x * 64;
    float local = 0.f, lc = 0.f;
    int cur = -1;
    for (int j = 0; j < 64; ++j) {
        const int n = base + j;
        if (n >= N_NODES) break;
        const int g = batch[n];
        if (g != cur) {
            if (cur >= 0) {
                unsafeAtomicAdd(&pooled[cur * 64 + t], local);
                if (t == 0) unsafeAtomicAdd(&cnt[cur], lc);
            }
            cur = g; local = 0.f; lc = 0.f;
        }
        local += h2[n * 64 + t];
        lc += 1.f;
    }
    if (cur >= 0) {
        unsafeAtomicAdd(&pooled[cur * 64 + t], local);
        if (t == 0) unsafeAtomicAdd(&cnt[cur], lc);
    }
}

__global__ __launch_bounds__(128) void head_kernel(
    const float* __restrict__ pooled, const float* __restrict__ cnt,
    const float* __restrict__ lin_w, const float* __restrict__ lin_b,
    float* __restrict__ out) {
    const int i = threadIdx.x;          // 0..127 -> (g, k)
    const int g = i >> 1, k = i & 1;
    float c = cnt[g];
    c = c > 1.f ? c : 1.f;
    float a = 0.f;
#pragma unroll
    for (int j = 0; j < 64; ++j) a = fmaf(pooled[g * 64 + j] / c, lin_w[j * 2 + k], a);
    out[i] = a + lin_b[k];
}

extern "C" void kernel_launch(void* const* d_in, const int* in_sizes, int n_in,
                              void* d_out, int out_size, void* d_ws, size_t ws_size,
                              hipStream_t stream) {
    const float* x     = (const float*)d_in[0];
    const int*   ei    = (const int*)d_in[1];
    const int*   batch = (const int*)d_in[2];
    const float* Wl1   = (const float*)d_in[3];
    const float* Wr1   = (const float*)d_in[4];
    const float* att1  = (const float*)d_in[5];
    const float* b1    = (const float*)d_in[6];
    const float* Wl2   = (const float*)d_in[7];
    const float* Wr2   = (const float*)d_in[8];
    const float* att2  = (const float*)d_in[9];
    const float* b2    = (const float*)d_in[10];
    const float* lin_w = (const float*)d_in[11];
    const float* lin_b = (const float*)d_in[12];

    float* ws = (float*)d_ws;
    float* xl       = ws;                          //  3,200,000
    float* xr       = ws + 3200000;                //  3,200,000
    float* h1       = ws + 6400000;                //  3,200,000 (reused as h2)
    int*   rows     = (int*)(ws + 9600000);        //  4,003,840 (50048*80)
    int*   deg      = (int*)(ws + 13603840);       //     50,048
    int*   countsRM = (int*)(ws + 13653888);       //    100,096 (256*391)
    int*   scanT    = (int*)(ws + 13753984);       //    100,096 (391*256)
    int*   totals   = (int*)(ws + 13854080);       //        512
    int*   bb       = (int*)(ws + 13854592);       //        512 (bucketBase)
    float* pooled   = ws + 13855104;               //      4,096  -- memset start
    float* cnt      = ws + 13859200;               //         64
    int*   sortedE  = (int*)(ws + 13859264);       //  1,600,000
    // total ~15.46M floats ~= 61.8 MB (ws is 256 MiB)

    // zero pooled + cnt only (build is atomic-free, needs no init)
    hipMemsetAsync(pooled, 0, (size_t)(4096 + 64) * sizeof(float), stream);

    // ---- adjacency build: atomic-free radix partition + expand ----
    count_kernel<<<NBLK, 256, 0, stream>>>(ei, countsRM);
    scan_bucket<<<NB, 256, 0, stream>>>(countsRM, scanT, totals);
    scan_total<<<1, 512, 0, stream>>>(totals, bb);
    scatter2_kernel<<<NBLK, 256, 0, stream>>>(ei, scanT, bb, sortedE);
    expand_kernel<<<NB, 256, 0, stream>>>(bb, sortedE, deg, rows);

    const int gblocks = (N_NODES + 63) / 64;   // 782

    // ---- layer 1 ----
    gemm_tiled<128><<<gblocks, 256, 0, stream>>>(x, Wl1, Wr1, xl, xr);
    node_l1<<<N_NODES / 4, 256, 0, stream>>>(deg, rows, xl, xr, att1, b1, h1);

    // ---- layer 2 (h2 reuses h1 buffer; gemm consumed h1 first) ----
    gemm_tiled<64><<<gblocks, 256, 0, stream>>>(h1, Wl2, Wr2, xl, xr);
    node_l2<<<N_NODES / 4, 256, 0, stream>>>(deg, rows, xl, xr, att2, b2, h1);

    // ---- pool + head ----
    pool_kernel<<<(N_NODES + 63) / 64, 64, 0, stream>>>(h1, batch, pooled, cnt);
    head_kernel<<<1, 128, 0, stream>>>(pooled, cnt, lin_w, lin_b, (float*)d_out);
}

// Round 8
// 330.979 us; speedup vs baseline: 1.4489x; 1.0904x over previous
//
#include <hip/hip_runtime.h>
#include <hip/hip_bf16.h>
#include <math.h>

#define N_NODES 50000
#define N_EDGES 1600000
#define N_GRAPHS 64
#define NB 391             // dst buckets of 128 nodes: b = dst >> 7
#define NBLK 256           // partition blocks
#define CHUNK 6250         // edges per partition block (256*6250 = 1.6M exactly)
#define ROW_STRIDE 80      // per-node adjacency capacity; Poisson(32) > 80: P~5e-13

// ---------------------------------------------------------------------------
// DPP cross-lane add helpers (VALU pipe, no LDS).
// ---------------------------------------------------------------------------
template <int CTRL>
__device__ __forceinline__ float dpp_add(float v) {
    int r = __builtin_amdgcn_update_dpp(0, __builtin_bit_cast(int, v), CTRL, 0xF, 0xF, true);
    return v + __builtin_bit_cast(float, r);
}

// sum over 8 consecutive lanes (after: all 8 hold the sum)
__device__ __forceinline__ float red8(float v) {
    v = dpp_add<0xB1>(v);    // quad_perm [1,0,3,2]  (xor 1)
    v = dpp_add<0x4E>(v);    // quad_perm [2,3,0,1]  (xor 2)
    v = dpp_add<0x141>(v);   // row_half_mirror      (other quad in 8-group)
    return v;
}

// sum over 16 consecutive lanes
__device__ __forceinline__ float red16(float v) {
    v = red8(v);
    v = dpp_add<0x140>(v);   // row_mirror           (other 8-group in row)
    return v;
}

__device__ __forceinline__ float4 lrelu4(float4 u) {
    // leakyrelu(u) = max(u, 0.2*u)
    float4 r;
    r.x = fmaxf(u.x, 0.2f * u.x);
    r.y = fmaxf(u.y, 0.2f * u.y);
    r.z = fmaxf(u.z, 0.2f * u.z);
    r.w = fmaxf(u.w, 0.2f * u.w);
    return r;
}

// ---------------------------------------------------------------------------
// Register-tiled dense transform: out = x @ [Wl | Wr].
// ---------------------------------------------------------------------------
template <int K>
__global__ __launch_bounds__(256) void gemm_tiled(
    const float* __restrict__ x, const float* __restrict__ Wl,
    const float* __restrict__ Wr, float* __restrict__ xl, float* __restrict__ xr) {
    __shared__ float xs[64][K + 1];
    const int t = threadIdx.x;
    const int base = blockIdx.x * 64;
    const int nf4 = 64 * K / 4;
    for (int f = t; f < nf4; f += 256) {
        const int row = f / (K / 4);
        const int c4 = f % (K / 4);
        float4 v = make_float4(0.f, 0.f, 0.f, 0.f);
        if (base + row < N_NODES)
            v = *(const float4*)(x + (size_t)(base + row) * K + c4 * 4);
        xs[row][c4 * 4 + 0] = v.x;
        xs[row][c4 * 4 + 1] = v.y;
        xs[row][c4 * 4 + 2] = v.z;
        xs[row][c4 * 4 + 3] = v.w;
    }
    __syncthreads();
    const int lane = t & 63;
    const int w = __builtin_amdgcn_readfirstlane(t >> 6);
    const float* __restrict__ W = (w < 2) ? Wl : Wr;
    const int cb = (w & 1) * 32;
    float acc[32];
#pragma unroll
    for (int j = 0; j < 32; ++j) acc[j] = 0.f;
#pragma unroll 2
    for (int k = 0; k < K; ++k) {
        const float xv = xs[lane][k];
        const float* __restrict__ Wrow = W + k * 64 + cb;
#pragma unroll
        for (int j = 0; j < 32; ++j) acc[j] = fmaf(xv, Wrow[j], acc[j]);
    }
    const int n = base + lane;
    if (n < N_NODES) {
        float* __restrict__ o = (w < 2) ? xl : xr;
#pragma unroll
        for (int j = 0; j < 32; j += 4) {
            float4 v = {acc[j], acc[j + 1], acc[j + 2], acc[j + 3]};
            *(float4*)(o + (size_t)n * 64 + cb + j) = v;
        }
    }
}

// ---------------------------------------------------------------------------
// Atomic-free radix partition of edges by dst bucket (d>>7).
// ---------------------------------------------------------------------------
__global__ __launch_bounds__(256) void count_kernel(
    const int* __restrict__ ei, int* __restrict__ countsRM) {
    __shared__ int h[NB];
    const int t = threadIdx.x;
    for (int k = t; k < NB; k += 256) h[k] = 0;
    __syncthreads();
    const int base = blockIdx.x * CHUNK;
    for (int e = base + t; e < base + CHUNK; e += 256)
        atomicAdd(&h[ei[N_EDGES + e] >> 7], 1);
    __syncthreads();
    for (int k = t; k < NB; k += 256) countsRM[blockIdx.x * NB + k] = h[k];
}

__global__ __launch_bounds__(256) void scan_bucket(
    const int* __restrict__ countsRM, int* __restrict__ scanT,
    int* __restrict__ totals) {
    __shared__ int tmp[256];
    const int b = blockIdx.x;
    const int t = threadIdx.x;
    const int v0 = countsRM[t * NB + b];
    tmp[t] = v0;
    __syncthreads();
    for (int off = 1; off < 256; off <<= 1) {
        int v = (t >= off) ? tmp[t - off] : 0;
        __syncthreads();
        tmp[t] += v;
        __syncthreads();
    }
    scanT[b * 256 + t] = tmp[t] - v0;   // exclusive
    if (t == 255) totals[b] = tmp[t];
}

__global__ __launch_bounds__(512) void scan_total(
    const int* __restrict__ totals, int* __restrict__ bucketBase) {
    __shared__ int tmp[512];
    const int t = threadIdx.x;
    const int v0 = (t < NB) ? totals[t] : 0;
    tmp[t] = v0;
    __syncthreads();
    for (int off = 1; off < 512; off <<= 1) {
        int v = (t >= off) ? tmp[t - off] : 0;
        __syncthreads();
        tmp[t] += v;
        __syncthreads();
    }
    if (t < NB) bucketBase[t] = tmp[t] - v0;
    if (t == NB - 1) bucketBase[NB] = tmp[t];
}

__global__ __launch_bounds__(256) void scatter2_kernel(
    const int* __restrict__ ei, const int* __restrict__ scanT,
    const int* __restrict__ bucketBase, int* __restrict__ sortedE) {
    __shared__ int cursor[NB];
    const int t = threadIdx.x;
    const int b = blockIdx.x;
    for (int k = t; k < NB; k += 256)
        cursor[k] = bucketBase[k] + scanT[k * 256 + b];
    __syncthreads();
    const int base = b * CHUNK;
    for (int e = base + t; e < base + CHUNK; e += 256) {
        const int s = ei[e];
        const int d = ei[N_EDGES + e];
        const int idx = atomicAdd(&cursor[d >> 7], 1);   // LDS atomic
        sortedE[idx] = (s << 7) | (d & 127);
    }
}

__global__ __launch_bounds__(256) void expand_kernel(
    const int* __restrict__ bucketBase, const int* __restrict__ sortedE,
    int* __restrict__ deg, int* __restrict__ rows) {
    __shared__ int ldeg[128];
    const int b = blockIdx.x;
    const int t = threadIdx.x;
    if (t < 128) ldeg[t] = 0;
    __syncthreads();
    const int beg = bucketBase[b];
    const int end = bucketBase[b + 1];
    const int node_base = b * 128;
    for (int i = beg + t; i < end; i += 256) {
        const int en = sortedE[i];
        const int ld = en & 127;
        const int pos = atomicAdd(&ldeg[ld], 1);
        if (pos < ROW_STRIDE) rows[(node_base + ld) * ROW_STRIDE + pos] = en >> 7;
    }
    __syncthreads();
    if (t < 128) {
        const int n = node_base + t;
        if (n < N_NODES) {
            int c = ldeg[t];
            deg[n] = c < ROW_STRIDE ? c : ROW_STRIDE;
        }
    }
}

// ---------------------------------------------------------------------------
// Node-centric GATv2, float4 layout: one wave per dst node, 16 lanes per edge
// (4 channels/lane), 4 edges per wave-instruction, 2 independent chains = 8
// edges in flight. Cross-group (shfl 16/32) reduction deferred to once/node.
// L1HEADS=true: score reduce over 8 lanes (per head); false: over 16 lanes.
// ---------------------------------------------------------------------------
template <bool L1HEADS>
__device__ __forceinline__ float edge_ev4(float4 a, float4 xr4, float4 at4, bool valid) {
    float4 u;
    u.x = a.x + xr4.x; u.y = a.y + xr4.y; u.z = a.z + xr4.z; u.w = a.w + xr4.w;
    float4 l = lrelu4(u);
    float v = at4.x * l.x;
    v = fmaf(at4.y, l.y, v);
    v = fmaf(at4.z, l.z, v);
    v = fmaf(at4.w, l.w, v);
    v = L1HEADS ? red8(v) : red16(v);
    float ev = __expf(v);
    return valid ? ev : 0.f;
}

template <bool L1HEADS>
__global__ __launch_bounds__(256) void node_layer(
    const int* __restrict__ deg, const int* __restrict__ rows,
    const float* __restrict__ xl, const float* __restrict__ xr,
    const float* __restrict__ att, const float* __restrict__ bias,
    float* __restrict__ hout) {
    const int n = (blockIdx.x * 256 + threadIdx.x) >> 6;
    const int lane = threadIdx.x & 63;
    const int sub = lane & 15;       // channel group: ch = sub*4 .. sub*4+3
    const int g = lane >> 4;         // edge group 0..3
    const float4 xr4 = *(const float4*)(xr + (size_t)n * 64 + sub * 4);
    const float4 xl4 = *(const float4*)(xl + (size_t)n * 64 + sub * 4);
    const float4 at4 = *(const float4*)(att + sub * 4);

    // self loop: count once (group 0 only)
    float ev = edge_ev4<L1HEADS>(xl4, xr4, at4, g == 0);
    float4 acc;
    acc.x = ev * xl4.x; acc.y = ev * xl4.y; acc.z = ev * xl4.z; acc.w = ev * xl4.w;
    float ssum = ev;

    const int cnt = __builtin_amdgcn_readfirstlane(deg[n]);
    const int* __restrict__ row = rows + n * ROW_STRIDE;
    for (int i = 0; i < cnt; i += 8) {
        const int e0 = i + g, e1 = i + 4 + g;
        const bool v0 = e0 < cnt, v1 = e1 < cnt;
        const int s0 = v0 ? row[e0] : 0;
        const int s1 = v1 ? row[e1] : 0;
        const float4 a0 = *(const float4*)(xl + (size_t)s0 * 64 + sub * 4);
        const float4 a1 = *(const float4*)(xl + (size_t)s1 * 64 + sub * 4);
        const float ev0 = edge_ev4<L1HEADS>(a0, xr4, at4, v0);
        const float ev1 = edge_ev4<L1HEADS>(a1, xr4, at4, v1);
        acc.x = fmaf(ev0, a0.x, acc.x); acc.x = fmaf(ev1, a1.x, acc.x);
        acc.y = fmaf(ev0, a0.y, acc.y); acc.y = fmaf(ev1, a1.y, acc.y);
        acc.z = fmaf(ev0, a0.z, acc.z); acc.z = fmaf(ev1, a1.z, acc.z);
        acc.w = fmaf(ev0, a0.w, acc.w); acc.w = fmaf(ev1, a1.w, acc.w);
        ssum += ev0 + ev1;
    }
    // combine the 4 edge groups (once per node)
    acc.x += __shfl_xor(acc.x, 16); acc.x += __shfl_xor(acc.x, 32);
    acc.y += __shfl_xor(acc.y, 16); acc.y += __shfl_xor(acc.y, 32);
    acc.z += __shfl_xor(acc.z, 16); acc.z += __shfl_xor(acc.z, 32);
    acc.w += __shfl_xor(acc.w, 16); acc.w += __shfl_xor(acc.w, 32);
    ssum  += __shfl_xor(ssum, 16);  ssum  += __shfl_xor(ssum, 32);
    if (g == 0) {
        const float inv = 1.f / (ssum + 1e-16f);
        const float4 b4 = *(const float4*)(bias + sub * 4);
        float4 o;
        o.x = acc.x * inv + b4.x;
        o.y = acc.y * inv + b4.y;
        o.z = acc.z * inv + b4.z;
        o.w = acc.w * inv + b4.w;
        o.x = o.x > 0.f ? o.x : expm1f(o.x);
        o.y = o.y > 0.f ? o.y : expm1f(o.y);
        o.z = o.z > 0.f ? o.z : expm1f(o.z);
        o.w = o.w > 0.f ? o.w : expm1f(o.w);
        *(float4*)(hout + (size_t)n * 64 + sub * 4) = o;
    }
}

// Mean-pool accumulation over sorted batch ids.
__global__ __launch_bounds__(64) void pool_kernel(
    const float* __restrict__ h2, const int* __restrict__ batch,
    float* __restrict__ pooled, float* __restrict__ cnt) {
    const int t = threadIdx.x;
    const int base = blockIdx.x * 64;
    float local = 0.f, lc = 0.f;
    int cur = -1;
    for (int j = 0; j < 64; ++j) {
        const int n = base + j;
        if (n >= N_NODES) break;
        const int g = batch[n];
        if (g != cur) {
            if (cur >= 0) {
                unsafeAtomicAdd(&pooled[cur * 64 + t], local);
                if (t == 0) unsafeAtomicAdd(&cnt[cur], lc);
            }
            cur = g; local = 0.f; lc = 0.f;
        }
        local += h2[n * 64 + t];
        lc += 1.f;
    }
    if (cur >= 0) {
        unsafeAtomicAdd(&pooled[cur * 64 + t], local);
        if (t == 0) unsafeAtomicAdd(&cnt[cur], lc);
    }
}

__global__ __launch_bounds__(128) void head_kernel(
    const float* __restrict__ pooled, const float* __restrict__ cnt,
    const float* __restrict__ lin_w, const float* __restrict__ lin_b,
    float* __restrict__ out) {
    const int i = threadIdx.x;          // 0..127 -> (g, k)
    const int g = i >> 1, k = i & 1;
    float c = cnt[g];
    c = c > 1.f ? c : 1.f;
    float a = 0.f;
#pragma unroll
    for (int j = 0; j < 64; ++j) a = fmaf(pooled[g * 64 + j] / c, lin_w[j * 2 + k], a);
    out[i] = a + lin_b[k];
}

extern "C" void kernel_launch(void* const* d_in, const int* in_sizes, int n_in,
                              void* d_out, int out_size, void* d_ws, size_t ws_size,
                              hipStream_t stream) {
    const float* x     = (const float*)d_in[0];
    const int*   ei    = (const int*)d_in[1];
    const int*   batch = (const int*)d_in[2];
    const float* Wl1   = (const float*)d_in[3];
    const float* Wr1   = (const float*)d_in[4];
    const float* att1  = (const float*)d_in[5];
    const float* b1    = (const float*)d_in[6];
    const float* Wl2   = (const float*)d_in[7];
    const float* Wr2   = (const float*)d_in[8];
    const float* att2  = (const float*)d_in[9];
    const float* b2    = (const float*)d_in[10];
    const float* lin_w = (const float*)d_in[11];
    const float* lin_b = (const float*)d_in[12];

    float* ws = (float*)d_ws;
    float* xl       = ws;                          //  3,200,000
    float* xr       = ws + 3200000;                //  3,200,000
    float* h1       = ws + 6400000;                //  3,200,000 (reused as h2)
    int*   rows     = (int*)(ws + 9600000);        //  4,003,840 (50048*80)
    int*   deg      = (int*)(ws + 13603840);       //     50,048
    int*   countsRM = (int*)(ws + 13653888);       //    100,096 (256*391)
    int*   scanT    = (int*)(ws + 13753984);       //    100,096 (391*256)
    int*   totals   = (int*)(ws + 13854080);       //        512
    int*   bb       = (int*)(ws + 13854592);       //        512 (bucketBase)
    float* pooled   = ws + 13855104;               //      4,096  -- memset start
    float* cnt      = ws + 13859200;               //         64
    int*   sortedE  = (int*)(ws + 13859264);       //  1,600,000
    // total ~15.46M floats ~= 61.8 MB (ws is 256 MiB)

    // zero pooled + cnt only (build is atomic-free, needs no init)
    hipMemsetAsync(pooled, 0, (size_t)(4096 + 64) * sizeof(float), stream);

    // ---- adjacency build: atomic-free radix partition + expand ----
    count_kernel<<<NBLK, 256, 0, stream>>>(ei, countsRM);
    scan_bucket<<<NB, 256, 0, stream>>>(countsRM, scanT, totals);
    scan_total<<<1, 512, 0, stream>>>(totals, bb);
    scatter2_kernel<<<NBLK, 256, 0, stream>>>(ei, scanT, bb, sortedE);
    expand_kernel<<<NB, 256, 0, stream>>>(bb, sortedE, deg, rows);

    const int gblocks = (N_NODES + 63) / 64;   // 782

    // ---- layer 1 ----
    gemm_tiled<128><<<gblocks, 256, 0, stream>>>(x, Wl1, Wr1, xl, xr);
    node_layer<true><<<N_NODES / 4, 256, 0, stream>>>(deg, rows, xl, xr, att1, b1, h1);

    // ---- layer 2 (h2 reuses h1 buffer; gemm consumed h1 first) ----
    gemm_tiled<64><<<gblocks, 256, 0, stream>>>(h1, Wl2, Wr2, xl, xr);
    node_layer<false><<<N_NODES / 4, 256, 0, stream>>>(deg, rows, xl, xr, att2, b2, h1);

    // ---- pool + head ----
    pool_kernel<<<(N_NODES + 63) / 64, 64, 0, stream>>>(h1, batch, pooled, cnt);
    head_kernel<<<1, 128, 0, stream>>>(pooled, cnt, lin_w, lin_b, (float*)d_out);
}

// Round 9
// 318.877 us; speedup vs baseline: 1.5039x; 1.0380x over previous
//
#include <hip/hip_runtime.h>
#include <hip/hip_bf16.h>
#include <math.h>

#define N_NODES 50000
#define N_EDGES 1600000
#define N_GRAPHS 64
#define NB 391             // dst buckets of 128 nodes: b = dst >> 7
#define NBLK 256           // partition blocks
#define CHUNK 6250         // edges per partition block (256*6250 = 1.6M exactly)
#define ROW_STRIDE 80      // per-node adjacency capacity; Poisson(32) > 80: P~5e-13

typedef unsigned int u32;

// ---------------------------------------------------------------------------
// DPP cross-lane add helpers (VALU pipe, no LDS).
// ---------------------------------------------------------------------------
template <int CTRL>
__device__ __forceinline__ float dpp_add(float v) {
    int r = __builtin_amdgcn_update_dpp(0, __builtin_bit_cast(int, v), CTRL, 0xF, 0xF, true);
    return v + __builtin_bit_cast(float, r);
}

// sum over 8 consecutive lanes
__device__ __forceinline__ float red8(float v) {
    v = dpp_add<0xB1>(v);    // quad_perm [1,0,3,2]
    v = dpp_add<0x4E>(v);    // quad_perm [2,3,0,1]
    v = dpp_add<0x141>(v);   // row_half_mirror
    return v;
}

// sum over 16 consecutive lanes
__device__ __forceinline__ float red16(float v) {
    v = red8(v);
    v = dpp_add<0x140>(v);   // row_mirror
    return v;
}

__device__ __forceinline__ float4 lrelu4(float4 u) {
    float4 r;
    r.x = fmaxf(u.x, 0.2f * u.x);
    r.y = fmaxf(u.y, 0.2f * u.y);
    r.z = fmaxf(u.z, 0.2f * u.z);
    r.w = fmaxf(u.w, 0.2f * u.w);
    return r;
}

// bf16x4 (two dwords, 2 bf16 each) -> float4 via shift/mask (4 VALU inst)
__device__ __forceinline__ float4 unpack_bf16x4(uint2 u) {
    float4 a;
    a.x = __builtin_bit_cast(float, u.x << 16);
    a.y = __builtin_bit_cast(float, u.x & 0xFFFF0000u);
    a.z = __builtin_bit_cast(float, u.y << 16);
    a.w = __builtin_bit_cast(float, u.y & 0xFFFF0000u);
    return a;
}

__device__ __forceinline__ u32 pack_bf16x2(float lo, float hi) {
    unsigned short l = __builtin_bit_cast(unsigned short, __float2bfloat16(lo));
    unsigned short h = __builtin_bit_cast(unsigned short, __float2bfloat16(hi));
    return (u32)l | ((u32)h << 16);
}

// ---------------------------------------------------------------------------
// Register-tiled dense transform: xlb(bf16) = x @ Wl, xr(f32) = x @ Wr.
// Block = 64 nodes, 4 waves; lane = node, wave = 32-col group; W rows are
// wave-uniform -> scalar loads; 32 independent accumulators.
// FUSE_COUNT: blocks >= gemmBlocks instead run the edge-bucket histogram
// (independent work; reuses the gemm's LDS allocation).
// ---------------------------------------------------------------------------
template <int K, bool FUSE_COUNT>
__global__ __launch_bounds__(256) void gemm_tiled(
    const float* __restrict__ x, const float* __restrict__ Wl,
    const float* __restrict__ Wr, u32* __restrict__ xlb, float* __restrict__ xr,
    const int* __restrict__ ei, int* __restrict__ countsRM, int gemmBlocks) {
    __shared__ float xs[64][K + 1];
    const int t = threadIdx.x;
    if (FUSE_COUNT && blockIdx.x >= gemmBlocks) {
        int* h = (int*)&xs[0][0];
        const int cb = blockIdx.x - gemmBlocks;
        for (int k = t; k < NB; k += 256) h[k] = 0;
        __syncthreads();
        const int base = cb * CHUNK;
        for (int e = base + t; e < base + CHUNK; e += 256)
            atomicAdd(&h[ei[N_EDGES + e] >> 7], 1);
        __syncthreads();
        for (int k = t; k < NB; k += 256) countsRM[cb * NB + k] = h[k];
        return;
    }
    const int base = blockIdx.x * 64;
    const int nf4 = 64 * K / 4;
    for (int f = t; f < nf4; f += 256) {
        const int row = f / (K / 4);
        const int c4 = f % (K / 4);
        float4 v = make_float4(0.f, 0.f, 0.f, 0.f);
        if (base + row < N_NODES)
            v = *(const float4*)(x + (size_t)(base + row) * K + c4 * 4);
        xs[row][c4 * 4 + 0] = v.x;
        xs[row][c4 * 4 + 1] = v.y;
        xs[row][c4 * 4 + 2] = v.z;
        xs[row][c4 * 4 + 3] = v.w;
    }
    __syncthreads();
    const int lane = t & 63;
    const int w = __builtin_amdgcn_readfirstlane(t >> 6);
    const float* __restrict__ W = (w < 2) ? Wl : Wr;
    const int cb = (w & 1) * 32;
    float acc[32];
#pragma unroll
    for (int j = 0; j < 32; ++j) acc[j] = 0.f;
#pragma unroll 2
    for (int k = 0; k < K; ++k) {
        const float xv = xs[lane][k];
        const float* __restrict__ Wrow = W + k * 64 + cb;
#pragma unroll
        for (int j = 0; j < 32; ++j) acc[j] = fmaf(xv, Wrow[j], acc[j]);
    }
    const int n = base + lane;
    if (n < N_NODES) {
        if (w < 2) {
            // bf16 pack: 32 cols -> 16 dwords -> 4 dwordx4 stores
            u32 pk[16];
#pragma unroll
            for (int j = 0; j < 32; j += 2) pk[j >> 1] = pack_bf16x2(acc[j], acc[j + 1]);
            uint4* dst = (uint4*)(xlb + (size_t)n * 32 + (w & 1) * 16);
#pragma unroll
            for (int j = 0; j < 4; ++j)
                dst[j] = make_uint4(pk[j * 4], pk[j * 4 + 1], pk[j * 4 + 2], pk[j * 4 + 3]);
        } else {
#pragma unroll
            for (int j = 0; j < 32; j += 4) {
                float4 v = {acc[j], acc[j + 1], acc[j + 2], acc[j + 3]};
                *(float4*)(xr + (size_t)n * 64 + cb + j) = v;
            }
        }
    }
}

// ---------------------------------------------------------------------------
// Atomic-free radix partition (scans + LDS-cursor scatter) + expand.
// ---------------------------------------------------------------------------
__global__ __launch_bounds__(256) void scan_bucket(
    const int* __restrict__ countsRM, int* __restrict__ scanT,
    int* __restrict__ totals) {
    __shared__ int tmp[256];
    const int b = blockIdx.x;
    const int t = threadIdx.x;
    const int v0 = countsRM[t * NB + b];
    tmp[t] = v0;
    __syncthreads();
    for (int off = 1; off < 256; off <<= 1) {
        int v = (t >= off) ? tmp[t - off] : 0;
        __syncthreads();
        tmp[t] += v;
        __syncthreads();
    }
    scanT[b * 256 + t] = tmp[t] - v0;   // exclusive
    if (t == 255) totals[b] = tmp[t];
}

__global__ __launch_bounds__(512) void scan_total(
    const int* __restrict__ totals, int* __restrict__ bucketBase) {
    __shared__ int tmp[512];
    const int t = threadIdx.x;
    const int v0 = (t < NB) ? totals[t] : 0;
    tmp[t] = v0;
    __syncthreads();
    for (int off = 1; off < 512; off <<= 1) {
        int v = (t >= off) ? tmp[t - off] : 0;
        __syncthreads();
        tmp[t] += v;
        __syncthreads();
    }
    if (t < NB) bucketBase[t] = tmp[t] - v0;
    if (t == NB - 1) bucketBase[NB] = tmp[t];
}

__global__ __launch_bounds__(256) void scatter2_kernel(
    const int* __restrict__ ei, const int* __restrict__ scanT,
    const int* __restrict__ bucketBase, int* __restrict__ sortedE) {
    __shared__ int cursor[NB];
    const int t = threadIdx.x;
    const int b = blockIdx.x;
    for (int k = t; k < NB; k += 256)
        cursor[k] = bucketBase[k] + scanT[k * 256 + b];
    __syncthreads();
    const int base = b * CHUNK;
    for (int e = base + t; e < base + CHUNK; e += 256) {
        const int s = ei[e];
        const int d = ei[N_EDGES + e];
        const int idx = atomicAdd(&cursor[d >> 7], 1);   // LDS atomic
        sortedE[idx] = (s << 7) | (d & 127);
    }
}

__global__ __launch_bounds__(256) void expand_kernel(
    const int* __restrict__ bucketBase, const int* __restrict__ sortedE,
    int* __restrict__ deg, int* __restrict__ rows) {
    __shared__ int ldeg[128];
    const int b = blockIdx.x;
    const int t = threadIdx.x;
    if (t < 128) ldeg[t] = 0;
    __syncthreads();
    const int beg = bucketBase[b];
    const int end = bucketBase[b + 1];
    const int node_base = b * 128;
    for (int i = beg + t; i < end; i += 256) {
        const int en = sortedE[i];
        const int ld = en & 127;
        const int pos = atomicAdd(&ldeg[ld], 1);
        if (pos < ROW_STRIDE) rows[(node_base + ld) * ROW_STRIDE + pos] = en >> 7;
    }
    __syncthreads();
    if (t < 128) {
        const int n = node_base + t;
        if (n < N_NODES) {
            int c = ldeg[t];
            deg[n] = c < ROW_STRIDE ? c : ROW_STRIDE;
        }
    }
}

// ---------------------------------------------------------------------------
// Node-centric GATv2, bf16-gather layout: one wave per dst node, 16 lanes per
// edge (4 ch/lane), 4 edges per wave-instruction, 2 chains = 8 edges in
// flight. Gathers are 8 B/lane (uint2 of 4 bf16); scores/acc stay f32.
// ---------------------------------------------------------------------------
template <bool L1HEADS>
__device__ __forceinline__ float edge_ev4(float4 a, float4 xr4, float4 at4, bool valid) {
    float4 u;
    u.x = a.x + xr4.x; u.y = a.y + xr4.y; u.z = a.z + xr4.z; u.w = a.w + xr4.w;
    float4 l = lrelu4(u);
    float v = at4.x * l.x;
    v = fmaf(at4.y, l.y, v);
    v = fmaf(at4.z, l.z, v);
    v = fmaf(at4.w, l.w, v);
    v = L1HEADS ? red8(v) : red16(v);
    float ev = __expf(v);
    return valid ? ev : 0.f;
}

template <bool L1HEADS>
__global__ __launch_bounds__(256) void node_layer(
    const int* __restrict__ deg, const int* __restrict__ rows,
    const u32* __restrict__ xlb, const float* __restrict__ xr,
    const float* __restrict__ att, const float* __restrict__ bias,
    float* __restrict__ hout) {
    const int n = (blockIdx.x * 256 + threadIdx.x) >> 6;
    const int lane = threadIdx.x & 63;
    const int sub = lane & 15;       // channel group: ch = sub*4 .. sub*4+3
    const int g = lane >> 4;         // edge group 0..3
    const float4 xr4 = *(const float4*)(xr + (size_t)n * 64 + sub * 4);
    const float4 xl4 = unpack_bf16x4(*(const uint2*)(xlb + (size_t)n * 32 + sub * 2));
    const float4 at4 = *(const float4*)(att + sub * 4);

    // self loop: count once (group 0 only)
    float ev = edge_ev4<L1HEADS>(xl4, xr4, at4, g == 0);
    float4 acc;
    acc.x = ev * xl4.x; acc.y = ev * xl4.y; acc.z = ev * xl4.z; acc.w = ev * xl4.w;
    float ssum = ev;

    const int cnt = __builtin_amdgcn_readfirstlane(deg[n]);
    const int* __restrict__ row = rows + n * ROW_STRIDE;
    for (int i = 0; i < cnt; i += 8) {
        const int e0 = i + g, e1 = i + 4 + g;
        const bool v0 = e0 < cnt, v1 = e1 < cnt;
        const int s0 = v0 ? row[e0] : 0;
        const int s1 = v1 ? row[e1] : 0;
        const float4 a0 = unpack_bf16x4(*(const uint2*)(xlb + (size_t)s0 * 32 + sub * 2));
        const float4 a1 = unpack_bf16x4(*(const uint2*)(xlb + (size_t)s1 * 32 + sub * 2));
        const float ev0 = edge_ev4<L1HEADS>(a0, xr4, at4, v0);
        const float ev1 = edge_ev4<L1HEADS>(a1, xr4, at4, v1);
        acc.x = fmaf(ev0, a0.x, acc.x); acc.x = fmaf(ev1, a1.x, acc.x);
        acc.y = fmaf(ev0, a0.y, acc.y); acc.y = fmaf(ev1, a1.y, acc.y);
        acc.z = fmaf(ev0, a0.z, acc.z); acc.z = fmaf(ev1, a1.z, acc.z);
        acc.w = fmaf(ev0, a0.w, acc.w); acc.w = fmaf(ev1, a1.w, acc.w);
        ssum += ev0 + ev1;
    }
    // combine the 4 edge groups (once per node)
    acc.x += __shfl_xor(acc.x, 16); acc.x += __shfl_xor(acc.x, 32);
    acc.y += __shfl_xor(acc.y, 16); acc.y += __shfl_xor(acc.y, 32);
    acc.z += __shfl_xor(acc.z, 16); acc.z += __shfl_xor(acc.z, 32);
    acc.w += __shfl_xor(acc.w, 16); acc.w += __shfl_xor(acc.w, 32);
    ssum  += __shfl_xor(ssum, 16);  ssum  += __shfl_xor(ssum, 32);
    if (g == 0) {
        const float inv = 1.f / (ssum + 1e-16f);
        const float4 b4 = *(const float4*)(bias + sub * 4);
        float4 o;
        o.x = acc.x * inv + b4.x;
        o.y = acc.y * inv + b4.y;
        o.z = acc.z * inv + b4.z;
        o.w = acc.w * inv + b4.w;
        o.x = o.x > 0.f ? o.x : expm1f(o.x);
        o.y = o.y > 0.f ? o.y : expm1f(o.y);
        o.z = o.z > 0.f ? o.z : expm1f(o.z);
        o.w = o.w > 0.f ? o.w : expm1f(o.w);
        *(float4*)(hout + (size_t)n * 64 + sub * 4) = o;
    }
}

// Mean-pool accumulation over sorted batch ids.
__global__ __launch_bounds__(64) void pool_kernel(
    const float* __restrict__ h2, const int* __restrict__ batch,
    float* __restrict__ pooled, float* __restrict__ cnt) {
    const int t = threadIdx.x;
    const int base = blockIdx.x * 64;
    float local = 0.f, lc = 0.f;
    int cur = -1;
    for (int j = 0; j < 64; ++j) {
        const int n = base + j;
        if (n >= N_NODES) break;
        const int g = batch[n];
        if (g != cur) {
            if (cur >= 0) {
                unsafeAtomicAdd(&pooled[cur * 64 + t], local);
                if (t == 0) unsafeAtomicAdd(&cnt[cur], lc);
            }
            cur = g; local = 0.f; lc = 0.f;
        }
        local += h2[n * 64 + t];
        lc += 1.f;
    }
    if (cur >= 0) {
        unsafeAtomicAdd(&pooled[cur * 64 + t], local);
        if (t == 0) unsafeAtomicAdd(&cnt[cur], lc);
    }
}

__global__ __launch_bounds__(128) void head_kernel(
    const float* __restrict__ pooled, const float* __restrict__ cnt,
    const float* __restrict__ lin_w, const float* __restrict__ lin_b,
    float* __restrict__ out) {
    const int i = threadIdx.x;          // 0..127 -> (g, k)
    const int g = i >> 1, k = i & 1;
    float c = cnt[g];
    c = c > 1.f ? c : 1.f;
    float a = 0.f;
#pragma unroll
    for (int j = 0; j < 64; ++j) a = fmaf(pooled[g * 64 + j] / c, lin_w[j * 2 + k], a);
    out[i] = a + lin_b[k];
}

extern "C" void kernel_launch(void* const* d_in, const int* in_sizes, int n_in,
                              void* d_out, int out_size, void* d_ws, size_t ws_size,
                              hipStream_t stream) {
    const float* x     = (const float*)d_in[0];
    const int*   ei    = (const int*)d_in[1];
    const int*   batch = (const int*)d_in[2];
    const float* Wl1   = (const float*)d_in[3];
    const float* Wr1   = (const float*)d_in[4];
    const float* att1  = (const float*)d_in[5];
    const float* b1    = (const float*)d_in[6];
    const float* Wl2   = (const float*)d_in[7];
    const float* Wr2   = (const float*)d_in[8];
    const float* att2  = (const float*)d_in[9];
    const float* b2    = (const float*)d_in[10];
    const float* lin_w = (const float*)d_in[11];
    const float* lin_b = (const float*)d_in[12];

    float* ws = (float*)d_ws;
    u32*   xlb      = (u32*)ws;                    //  1,600,000 dwords (bf16 table)
    float* xr       = ws + 1600000;                //  3,200,000
    float* h1       = ws + 4800000;                //  3,200,000 (reused as h2)
    int*   rows     = (int*)(ws + 8000000);        //  4,003,840 (50048*80)
    int*   deg      = (int*)(ws + 12003840);       //     50,048
    int*   countsRM = (int*)(ws + 12053888);       //    100,096 (256*391)
    int*   scanT    = (int*)(ws + 12153984);       //    100,096 (391*256)
    int*   totals   = (int*)(ws + 12254080);       //        512
    int*   bb       = (int*)(ws + 12254592);       //        512 (bucketBase)
    float* pooled   = ws + 12255104;               //      4,096  -- memset start
    float* cnt      = ws + 12259200;               //         64
    int*   sortedE  = (int*)(ws + 12259264);       //  1,600,000
    // total ~13.9M floats ~= 55 MB (ws is 256 MiB)

    // zero pooled + cnt only (build is atomic-free, needs no init)
    hipMemsetAsync(pooled, 0, (size_t)(4096 + 64) * sizeof(float), stream);

    const int gblocks = (N_NODES + 63) / 64;   // 782

    // ---- layer-1 gemm fused with edge-bucket histogram (independent) ----
    gemm_tiled<128, true><<<gblocks + NBLK, 256, 0, stream>>>(
        x, Wl1, Wr1, xlb, xr, ei, countsRM, gblocks);

    // ---- adjacency build: scans + LDS-cursor scatter + expand ----
    scan_bucket<<<NB, 256, 0, stream>>>(countsRM, scanT, totals);
    scan_total<<<1, 512, 0, stream>>>(totals, bb);
    scatter2_kernel<<<NBLK, 256, 0, stream>>>(ei, scanT, bb, sortedE);
    expand_kernel<<<NB, 256, 0, stream>>>(bb, sortedE, deg, rows);

    // ---- layer 1 node pass ----
    node_layer<true><<<N_NODES / 4, 256, 0, stream>>>(deg, rows, xlb, xr, att1, b1, h1);

    // ---- layer 2 (h2 reuses h1 buffer; gemm consumed h1 first) ----
    gemm_tiled<64, false><<<gblocks, 256, 0, stream>>>(
        h1, Wl2, Wr2, xlb, xr, nullptr, nullptr, gblocks);
    node_layer<false><<<N_NODES / 4, 256, 0, stream>>>(deg, rows, xlb, xr, att2, b2, h1);

    // ---- pool + head ----
    pool_kernel<<<(N_NODES + 63) / 64, 64, 0, stream>>>(h1, batch, pooled, cnt);
    head_kernel<<<1, 128, 0, stream>>>(pooled, cnt, lin_w, lin_b, (float*)d_out);
}

// Round 10
// 311.438 us; speedup vs baseline: 1.5398x; 1.0239x over previous
//
#include <hip/hip_runtime.h>
#include <hip/hip_bf16.h>
#include <math.h>

#define N_NODES 50000
#define N_EDGES 1600000
#define N_GRAPHS 64
#define NB 391             // dst buckets of 128 nodes: b = dst >> 7
#define NBLK 256           // partition blocks
#define CHUNK 6250         // edges per partition block (256*6250 = 1.6M exactly)
#define ROW_STRIDE 80      // per-node adjacency capacity (multiple of 8)
#define SENT 50047         // sentinel node: al[SENT] = -1e30 -> exp(score) = 0

typedef unsigned int u32;

__device__ __forceinline__ float bcf(u32 u) { return __builtin_bit_cast(float, u); }

// ---------------------------------------------------------------------------
// DPP cross-lane add helpers (VALU pipe, no LDS).
// ---------------------------------------------------------------------------
template <int CTRL>
__device__ __forceinline__ float dpp_add(float v) {
    int r = __builtin_amdgcn_update_dpp(0, __builtin_bit_cast(int, v), CTRL, 0xF, 0xF, true);
    return v + __builtin_bit_cast(float, r);
}

__device__ __forceinline__ u32 pack_bf16x2(float lo, float hi) {
    unsigned short l = __builtin_bit_cast(unsigned short, __float2bfloat16(lo));
    unsigned short h = __builtin_bit_cast(unsigned short, __float2bfloat16(hi));
    return (u32)l | ((u32)h << 16);
}

// ---------------------------------------------------------------------------
// Register-tiled dense transform: xlb(bf16) = x @ Wl, xr(f32) = x @ Wr.
// Epilogue also emits al[n] = att . xl and ar[n] = att . xr as float2
// per-32-col partials (L1: the two heads; L2: two halves to be summed).
// FUSE_COUNT: blocks >= gemmBlocks run the edge-bucket histogram instead.
// ---------------------------------------------------------------------------
template <int K, bool FUSE_COUNT>
__global__ __launch_bounds__(256) void gemm_tiled(
    const float* __restrict__ x, const float* __restrict__ Wl,
    const float* __restrict__ Wr, const float* __restrict__ att,
    u32* __restrict__ xlb, float* __restrict__ xr,
    float* __restrict__ alb, float* __restrict__ arb,
    const int* __restrict__ ei, int* __restrict__ countsRM, int gemmBlocks) {
    __shared__ float xs[64][K + 1];
    const int t = threadIdx.x;
    if (FUSE_COUNT && blockIdx.x >= gemmBlocks) {
        int* h = (int*)&xs[0][0];
        const int cb = blockIdx.x - gemmBlocks;
        for (int k = t; k < NB; k += 256) h[k] = 0;
        __syncthreads();
        const int base = cb * CHUNK;
        for (int e = base + t; e < base + CHUNK; e += 256)
            atomicAdd(&h[ei[N_EDGES + e] >> 7], 1);
        __syncthreads();
        for (int k = t; k < NB; k += 256) countsRM[cb * NB + k] = h[k];
        return;
    }
    const int base = blockIdx.x * 64;
    const int nf4 = 64 * K / 4;
    for (int f = t; f < nf4; f += 256) {
        const int row = f / (K / 4);
        const int c4 = f % (K / 4);
        float4 v = make_float4(0.f, 0.f, 0.f, 0.f);
        if (base + row < N_NODES)
            v = *(const float4*)(x + (size_t)(base + row) * K + c4 * 4);
        xs[row][c4 * 4 + 0] = v.x;
        xs[row][c4 * 4 + 1] = v.y;
        xs[row][c4 * 4 + 2] = v.z;
        xs[row][c4 * 4 + 3] = v.w;
    }
    __syncthreads();
    const int lane = t & 63;
    const int w = __builtin_amdgcn_readfirstlane(t >> 6);
    const float* __restrict__ W = (w < 2) ? Wl : Wr;
    const int cb = (w & 1) * 32;
    float acc[32];
#pragma unroll
    for (int j = 0; j < 32; ++j) acc[j] = 0.f;
#pragma unroll 2
    for (int k = 0; k < K; ++k) {
        const float xv = xs[lane][k];
        const float* __restrict__ Wrow = W + k * 64 + cb;
#pragma unroll
        for (int j = 0; j < 32; ++j) acc[j] = fmaf(xv, Wrow[j], acc[j]);
    }
    const int n = base + lane;
    if (n < N_NODES) {
        // att-dot partial for this 32-col group (wave-uniform att reads)
        float av = 0.f;
#pragma unroll
        for (int j = 0; j < 32; ++j) av = fmaf(att[cb + j], acc[j], av);
        if (w < 2) {
            alb[(size_t)n * 2 + (w & 1)] = av;
            u32 pk[16];
#pragma unroll
            for (int j = 0; j < 32; j += 2) pk[j >> 1] = pack_bf16x2(acc[j], acc[j + 1]);
            uint4* dst = (uint4*)(xlb + (size_t)n * 32 + (w & 1) * 16);
#pragma unroll
            for (int j = 0; j < 4; ++j)
                dst[j] = make_uint4(pk[j * 4], pk[j * 4 + 1], pk[j * 4 + 2], pk[j * 4 + 3]);
        } else {
            arb[(size_t)n * 2 + (w & 1)] = av;
#pragma unroll
            for (int j = 0; j < 32; j += 4) {
                float4 v = {acc[j], acc[j + 1], acc[j + 2], acc[j + 3]};
                *(float4*)(xr + (size_t)n * 64 + cb + j) = v;
            }
        }
    }
}

// ---------------------------------------------------------------------------
// Atomic-free radix partition (scans + LDS-cursor scatter) + expand.
// ---------------------------------------------------------------------------
__global__ __launch_bounds__(256) void scan_bucket(
    const int* __restrict__ countsRM, int* __restrict__ scanT,
    int* __restrict__ totals) {
    __shared__ int tmp[256];
    const int b = blockIdx.x;
    const int t = threadIdx.x;
    const int v0 = countsRM[t * NB + b];
    tmp[t] = v0;
    __syncthreads();
    for (int off = 1; off < 256; off <<= 1) {
        int v = (t >= off) ? tmp[t - off] : 0;
        __syncthreads();
        tmp[t] += v;
        __syncthreads();
    }
    scanT[b * 256 + t] = tmp[t] - v0;   // exclusive
    if (t == 255) totals[b] = tmp[t];
}

__global__ __launch_bounds__(512) void scan_total(
    const int* __restrict__ totals, int* __restrict__ bucketBase,
    float* __restrict__ alb) {
    __shared__ int tmp[512];
    const int t = threadIdx.x;
    const int v0 = (t < NB) ? totals[t] : 0;
    tmp[t] = v0;
    __syncthreads();
    for (int off = 1; off < 512; off <<= 1) {
        int v = (t >= off) ? tmp[t - off] : 0;
        __syncthreads();
        tmp[t] += v;
        __syncthreads();
    }
    if (t < NB) bucketBase[t] = tmp[t] - v0;
    if (t == NB - 1) bucketBase[NB] = tmp[t];
    if (t == 0) { alb[(size_t)SENT * 2] = -1e30f; alb[(size_t)SENT * 2 + 1] = -1e30f; }
}

__global__ __launch_bounds__(256) void scatter2_kernel(
    const int* __restrict__ ei, const int* __restrict__ scanT,
    const int* __restrict__ bucketBase, int* __restrict__ sortedE) {
    __shared__ int cursor[NB];
    const int t = threadIdx.x;
    const int b = blockIdx.x;
    for (int k = t; k < NB; k += 256)
        cursor[k] = bucketBase[k] + scanT[k * 256 + b];
    __syncthreads();
    const int base = b * CHUNK;
    for (int e = base + t; e < base + CHUNK; e += 256) {
        const int s = ei[e];
        const int d = ei[N_EDGES + e];
        const int idx = atomicAdd(&cursor[d >> 7], 1);   // LDS atomic
        sortedE[idx] = (s << 7) | (d & 127);
    }
}

// Expand: self-loop pre-seeded as entry 0; rows padded to x8 with SENT
// (sentinel edges get exp(score)=0 -> no validity logic in node_layer).
__global__ __launch_bounds__(256) void expand_kernel(
    const int* __restrict__ bucketBase, const int* __restrict__ sortedE,
    int* __restrict__ deg, int* __restrict__ rows) {
    __shared__ int ldeg[128];
    const int b = blockIdx.x;
    const int t = threadIdx.x;
    const int node_base = b * 128;
    if (t < 128) {
        const int n = node_base + t;
        ldeg[t] = 1;
        if (n < N_NODES) rows[(size_t)n * ROW_STRIDE] = n;   // self loop
    }
    __syncthreads();
    const int beg = bucketBase[b];
    const int end = bucketBase[b + 1];
    for (int i = beg + t; i < end; i += 256) {
        const int en = sortedE[i];
        const int ld = en & 127;
        const int pos = atomicAdd(&ldeg[ld], 1);
        if (pos < ROW_STRIDE) rows[(size_t)(node_base + ld) * ROW_STRIDE + pos] = en >> 7;
    }
    __syncthreads();
    if (t < 128) {
        const int n = node_base + t;
        if (n < N_NODES) {
            int c = ldeg[t];
            c = c < ROW_STRIDE ? c : ROW_STRIDE;
            const int cp = (c + 7) & ~7;
            for (int j = c; j < cp; ++j) rows[(size_t)n * ROW_STRIDE + j] = SENT;
            deg[n] = cp;
        }
    }
}

// ---------------------------------------------------------------------------
// Node-centric GATv2: one wave per dst node, 8 lanes/edge (8 ch/lane, bf16
// uint4 gathers), 8 edges per wave-instruction. Score via lrelu decomposition
//   score = 0.6*(al_s + ar_d) + 0.4 * sum_c att_c * |xl_c + xr_c|
// with al/ar precomputed per node -> per channel: 1 add + 1 fma(|.|).
// Sentinel rows give ev=0; no branches in the loop.
// ---------------------------------------------------------------------------
template <bool L1>
__global__ __launch_bounds__(256) void node_layer(
    const int* __restrict__ deg, const int* __restrict__ rows,
    const u32* __restrict__ xlb, const float* __restrict__ xr,
    const float* __restrict__ alb, const float* __restrict__ arb,
    const float* __restrict__ att, const float* __restrict__ bias,
    float* __restrict__ hout) {
    const int n = (blockIdx.x * 256 + threadIdx.x) >> 6;
    const int lane = threadIdx.x & 63;
    const int sub = lane & 7;        // channel octet: ch = sub*8 .. +7
    const int g = lane >> 3;         // edge slot 0..7
    const float4 xra = *(const float4*)(xr + (size_t)n * 64 + sub * 8);
    const float4 xrb = *(const float4*)(xr + (size_t)n * 64 + sub * 8 + 4);
    const float4 ata = *(const float4*)(att + sub * 8);
    const float4 atb = *(const float4*)(att + sub * 8 + 4);
    const float2 ar2 = *(const float2*)(arb + (size_t)n * 2);
    const float based = 0.6f * (L1 ? ((sub & 4) ? ar2.y : ar2.x) : (ar2.x + ar2.y));

    float c0 = 0.f, c1 = 0.f, c2 = 0.f, c3 = 0.f;
    float c4 = 0.f, c5 = 0.f, c6 = 0.f, c7 = 0.f;
    float ssum = 0.f;
    const int cp = __builtin_amdgcn_readfirstlane(deg[n]);
    const int* __restrict__ row = rows + (size_t)n * ROW_STRIDE;
    for (int i = 0; i < cp; i += 8) {
        const int s = row[i + g];
        float als;
        if (L1) {
            als = alb[(size_t)s * 2 + ((sub >> 2) & 1)];
        } else {
            const float2 a2 = *(const float2*)(alb + (size_t)s * 2);
            als = a2.x + a2.y;
        }
        const uint4 r4 = *(const uint4*)(xlb + (size_t)s * 32 + sub * 4);
        const float a0 = bcf(r4.x << 16), a1 = bcf(r4.x & 0xFFFF0000u);
        const float a2f = bcf(r4.y << 16), a3 = bcf(r4.y & 0xFFFF0000u);
        const float a4 = bcf(r4.z << 16), a5 = bcf(r4.z & 0xFFFF0000u);
        const float a6 = bcf(r4.w << 16), a7 = bcf(r4.w & 0xFFFF0000u);
        float v = ata.x * fabsf(a0 + xra.x);
        v = fmaf(ata.y, fabsf(a1 + xra.y), v);
        v = fmaf(ata.z, fabsf(a2f + xra.z), v);
        v = fmaf(ata.w, fabsf(a3 + xra.w), v);
        v = fmaf(atb.x, fabsf(a4 + xrb.x), v);
        v = fmaf(atb.y, fabsf(a5 + xrb.y), v);
        v = fmaf(atb.z, fabsf(a6 + xrb.z), v);
        v = fmaf(atb.w, fabsf(a7 + xrb.w), v);
        v = dpp_add<0xB1>(v);            // xor 1
        v = dpp_add<0x4E>(v);            // xor 2  (L1: 4-lane head reduce done)
        if (!L1) v = dpp_add<0x141>(v);  // row_half_mirror: 8-lane reduce
        const float ev = __expf(fmaf(0.6f, als, fmaf(0.4f, v, based)));
        c0 = fmaf(ev, a0, c0); c1 = fmaf(ev, a1, c1);
        c2 = fmaf(ev, a2f, c2); c3 = fmaf(ev, a3, c3);
        c4 = fmaf(ev, a4, c4); c5 = fmaf(ev, a5, c5);
        c6 = fmaf(ev, a6, c6); c7 = fmaf(ev, a7, c7);
        ssum += ev;
    }
    // combine the 8 edge slots: exact xor over lane bits 3,4,5
#define XRED(x) x += __shfl_xor(x, 8); x += __shfl_xor(x, 16); x += __shfl_xor(x, 32);
    XRED(c0) XRED(c1) XRED(c2) XRED(c3) XRED(c4) XRED(c5) XRED(c6) XRED(c7) XRED(ssum)
#undef XRED
    if (g == 0) {
        const float inv = 1.f / (ssum + 1e-16f);
        const float4 ba = *(const float4*)(bias + sub * 8);
        const float4 bb = *(const float4*)(bias + sub * 8 + 4);
        float o[8] = {c0 * inv + ba.x, c1 * inv + ba.y, c2 * inv + ba.z, c3 * inv + ba.w,
                      c4 * inv + bb.x, c5 * inv + bb.y, c6 * inv + bb.z, c7 * inv + bb.w};
#pragma unroll
        for (int j = 0; j < 8; ++j) o[j] = o[j] > 0.f ? o[j] : expm1f(o[j]);
        *(float4*)(hout + (size_t)n * 64 + sub * 8) = make_float4(o[0], o[1], o[2], o[3]);
        *(float4*)(hout + (size_t)n * 64 + sub * 8 + 4) = make_float4(o[4], o[5], o[6], o[7]);
    }
}

// Mean-pool accumulation over sorted batch ids.
__global__ __launch_bounds__(64) void pool_kernel(
    const float* __restrict__ h2, const int* __restrict__ batch,
    float* __restrict__ pooled, float* __restrict__ cnt) {
    const int t = threadIdx.x;
    const int base = blockIdx.x * 64;
    float local = 0.f, lc = 0.f;
    int cur = -1;
    for (int j = 0; j < 64; ++j) {
        const int n = base + j;
        if (n >= N_NODES) break;
        const int g = batch[n];
        if (g != cur) {
            if (cur >= 0) {
                unsafeAtomicAdd(&pooled[cur * 64 + t], local);
                if (t == 0) unsafeAtomicAdd(&cnt[cur], lc);
            }
            cur = g; local = 0.f; lc = 0.f;
        }
        local += h2[n * 64 + t];
        lc += 1.f;
    }
    if (cur >= 0) {
        unsafeAtomicAdd(&pooled[cur * 64 + t], local);
        if (t == 0) unsafeAtomicAdd(&cnt[cur], lc);
    }
}

__global__ __launch_bounds__(128) void head_kernel(
    const float* __restrict__ pooled, const float* __restrict__ cnt,
    const float* __restrict__ lin_w, const float* __restrict__ lin_b,
    float* __restrict__ out) {
    const int i = threadIdx.x;          // 0..127 -> (g, k)
    const int g = i >> 1, k = i & 1;
    float c = cnt[g];
    c = c > 1.f ? c : 1.f;
    float a = 0.f;
#pragma unroll
    for (int j = 0; j < 64; ++j) a = fmaf(pooled[g * 64 + j] / c, lin_w[j * 2 + k], a);
    out[i] = a + lin_b[k];
}

extern "C" void kernel_launch(void* const* d_in, const int* in_sizes, int n_in,
                              void* d_out, int out_size, void* d_ws, size_t ws_size,
                              hipStream_t stream) {
    const float* x     = (const float*)d_in[0];
    const int*   ei    = (const int*)d_in[1];
    const int*   batch = (const int*)d_in[2];
    const float* Wl1   = (const float*)d_in[3];
    const float* Wr1   = (const float*)d_in[4];
    const float* att1  = (const float*)d_in[5];
    const float* b1    = (const float*)d_in[6];
    const float* Wl2   = (const float*)d_in[7];
    const float* Wr2   = (const float*)d_in[8];
    const float* att2  = (const float*)d_in[9];
    const float* b2    = (const float*)d_in[10];
    const float* lin_w = (const float*)d_in[11];
    const float* lin_b = (const float*)d_in[12];

    float* ws = (float*)d_ws;
    u32*   xlb      = (u32*)ws;                    //  1,601,536 (50048*32 bf16 dwords)
    float* xr       = ws + 1601536;                //  3,200,000
    float* h1       = ws + 4801536;                //  3,200,000 (reused as h2)
    float* alb      = ws + 8001536;                //    100,096 (50048*2)
    float* arb      = ws + 8101632;                //    100,096
    int*   rows     = (int*)(ws + 8201728);        //  4,003,840 (50048*80)
    int*   deg      = (int*)(ws + 12205568);       //     50,048
    int*   countsRM = (int*)(ws + 12255616);       //    100,096 (256*391)
    int*   scanT    = (int*)(ws + 12355712);       //    100,096 (391*256)
    int*   totals   = (int*)(ws + 12455808);       //        512
    int*   bb       = (int*)(ws + 12456320);       //        512 (bucketBase)
    float* pooled   = ws + 12456832;               //      4,096  -- memset start
    float* cnt      = ws + 12460928;               //         64
    int*   sortedE  = (int*)(ws + 12460992);       //  1,600,000
    // total ~14.06M floats ~= 56 MB (ws is 256 MiB)

    // zero pooled + cnt only (build is atomic-free, needs no init)
    hipMemsetAsync(pooled, 0, (size_t)(4096 + 64) * sizeof(float), stream);

    const int gblocks = (N_NODES + 63) / 64;   // 782

    // ---- layer-1 gemm fused with edge-bucket histogram (independent) ----
    gemm_tiled<128, true><<<gblocks + NBLK, 256, 0, stream>>>(
        x, Wl1, Wr1, att1, xlb, xr, alb, arb, ei, countsRM, gblocks);

    // ---- adjacency build: scans + LDS-cursor scatter + expand ----
    scan_bucket<<<NB, 256, 0, stream>>>(countsRM, scanT, totals);
    scan_total<<<1, 512, 0, stream>>>(totals, bb, alb);
    scatter2_kernel<<<NBLK, 256, 0, stream>>>(ei, scanT, bb, sortedE);
    expand_kernel<<<NB, 256, 0, stream>>>(bb, sortedE, deg, rows);

    // ---- layer 1 node pass ----
    node_layer<true><<<N_NODES / 4, 256, 0, stream>>>(
        deg, rows, xlb, xr, alb, arb, att1, b1, h1);

    // ---- layer 2 (h2 reuses h1 buffer; gemm consumed h1 first) ----
    gemm_tiled<64, false><<<gblocks, 256, 0, stream>>>(
        h1, Wl2, Wr2, att2, xlb, xr, alb, arb, nullptr, nullptr, gblocks);
    node_layer<false><<<N_NODES / 4, 256, 0, stream>>>(
        deg, rows, xlb, xr, alb, arb, att2, b2, h1);

    // ---- pool + head ----
    pool_kernel<<<(N_NODES + 63) / 64, 64, 0, stream>>>(h1, batch, pooled, cnt);
    head_kernel<<<1, 128, 0, stream>>>(pooled, cnt, lin_w, lin_b, (float*)d_out);
}

// Round 11
// 302.809 us; speedup vs baseline: 1.5837x; 1.0285x over previous
//
#include <hip/hip_runtime.h>
#include <hip/hip_bf16.h>
#include <math.h>

#define N_NODES 50000
#define N_EDGES 1600000
#define N_GRAPHS 64
#define NB 391             // dst buckets of 128 nodes: b = dst >> 7
#define NBLK 256           // partition blocks
#define CHUNK 6250         // edges per partition block (256*6250 = 1.6M exactly)
#define ROW_STRIDE 80      // per-node adjacency capacity (multiple of 8)
#define SENT 50047         // sentinel node: al[SENT] = -1e30 -> exp(score) = 0

typedef unsigned int u32;

__device__ __forceinline__ float bcf(u32 u) { return __builtin_bit_cast(float, u); }

template <int CTRL>
__device__ __forceinline__ float dpp_add(float v) {
    int r = __builtin_amdgcn_update_dpp(0, __builtin_bit_cast(int, v), CTRL, 0xF, 0xF, true);
    return v + __builtin_bit_cast(float, r);
}

__device__ __forceinline__ u32 pack_bf16x2(float lo, float hi) {
    unsigned short l = __builtin_bit_cast(unsigned short, __float2bfloat16(lo));
    unsigned short h = __builtin_bit_cast(unsigned short, __float2bfloat16(hi));
    return (u32)l | ((u32)h << 16);
}

// ---------------------------------------------------------------------------
// Edge-bucket histogram (separate, small-LDS -> high occupancy).
// ---------------------------------------------------------------------------
__global__ __launch_bounds__(256) void count_kernel(
    const int* __restrict__ ei, int* __restrict__ countsRM) {
    __shared__ int h[NB];
    const int t = threadIdx.x;
    for (int k = t; k < NB; k += 256) h[k] = 0;
    __syncthreads();
    const int base = blockIdx.x * CHUNK;
    for (int e = base + t; e < base + CHUNK; e += 256)
        atomicAdd(&h[ei[N_EDGES + e] >> 7], 1);
    __syncthreads();
    for (int k = t; k < NB; k += 256) countsRM[blockIdx.x * NB + k] = h[k];
}

__global__ __launch_bounds__(256) void scan_bucket(
    const int* __restrict__ countsRM, int* __restrict__ scanT,
    int* __restrict__ totals) {
    __shared__ int tmp[256];
    const int b = blockIdx.x;
    const int t = threadIdx.x;
    const int v0 = countsRM[t * NB + b];
    tmp[t] = v0;
    __syncthreads();
    for (int off = 1; off < 256; off <<= 1) {
        int v = (t >= off) ? tmp[t - off] : 0;
        __syncthreads();
        tmp[t] += v;
        __syncthreads();
    }
    scanT[b * 256 + t] = tmp[t] - v0;   // exclusive
    if (t == 255) totals[b] = tmp[t];
}

__global__ __launch_bounds__(512) void scan_total(
    const int* __restrict__ totals, int* __restrict__ bucketBase,
    float* __restrict__ alb) {
    __shared__ int tmp[512];
    const int t = threadIdx.x;
    const int v0 = (t < NB) ? totals[t] : 0;
    tmp[t] = v0;
    __syncthreads();
    for (int off = 1; off < 512; off <<= 1) {
        int v = (t >= off) ? tmp[t - off] : 0;
        __syncthreads();
        tmp[t] += v;
        __syncthreads();
    }
    if (t < NB) bucketBase[t] = tmp[t] - v0;
    if (t == NB - 1) bucketBase[NB] = tmp[t];
    // L1-layout sentinel (indices 100094/100095; gemm writes only < 100000)
    if (t == 0) { alb[(size_t)SENT * 2] = -1e30f; alb[(size_t)SENT * 2 + 1] = -1e30f; }
}

// ---------------------------------------------------------------------------
// Register-tiled dense transform, K-chunked (LDS 64x65 f32 = 16.6 KB -> 8
// blocks/CU). xlb(bf16) = x @ Wl, xr(f32) = x @ Wr; epilogue emits att-dots
// al/ar. K==64 (layer 2): al written PRE-SUMMED (single float per node) and
// block 0 sets the L2 sentinel. FUSE_SCATTER: blocks >= gemmBlocks run the
// radix-scatter pass (independent work; LDS aliased onto xs).
// ---------------------------------------------------------------------------
template <int K, bool FUSE_SCATTER>
__global__ __launch_bounds__(256) void gemm_tiled(
    const float* __restrict__ x, const float* __restrict__ Wl,
    const float* __restrict__ Wr, const float* __restrict__ att,
    u32* __restrict__ xlb, float* __restrict__ xr,
    float* __restrict__ alb, float* __restrict__ arb,
    const int* __restrict__ ei, const int* __restrict__ scanT,
    const int* __restrict__ bb, int* __restrict__ sortedE, int gemmBlocks) {
    __shared__ float xs[64][65];     // +1 pad: scalar stage-writes 2 lanes/bank
    __shared__ float als[64];
    const int t = threadIdx.x;
    if (FUSE_SCATTER && blockIdx.x >= gemmBlocks) {
        int* cursor = (int*)&xs[0][0];
        const int b = blockIdx.x - gemmBlocks;
        for (int k = t; k < NB; k += 256)
            cursor[k] = bb[k] + scanT[k * 256 + b];
        __syncthreads();
        const int base = b * CHUNK;
        for (int e = base + t; e < base + CHUNK; e += 256) {
            const int s = ei[e];
            const int d = ei[N_EDGES + e];
            const int idx = atomicAdd(&cursor[d >> 7], 1);   // LDS atomic
            sortedE[idx] = (s << 7) | (d & 127);
        }
        return;
    }
    const int base = blockIdx.x * 64;
    const int lane = t & 63;
    const int w = __builtin_amdgcn_readfirstlane(t >> 6);
    const float* __restrict__ W = (w < 2) ? Wl : Wr;
    const int cb = (w & 1) * 32;
    float acc[32];
#pragma unroll
    for (int j = 0; j < 32; ++j) acc[j] = 0.f;
#pragma unroll
    for (int c = 0; c < K / 64; ++c) {
        if (c) __syncthreads();
        // stage 64x64 chunk, coalesced float4 reads, scalar LDS writes
        for (int f = t; f < 1024; f += 256) {
            const int row = f >> 4;
            const int c4 = f & 15;
            float4 v = make_float4(0.f, 0.f, 0.f, 0.f);
            if (base + row < N_NODES)
                v = *(const float4*)(x + (size_t)(base + row) * K + c * 64 + c4 * 4);
            xs[row][c4 * 4 + 0] = v.x;
            xs[row][c4 * 4 + 1] = v.y;
            xs[row][c4 * 4 + 2] = v.z;
            xs[row][c4 * 4 + 3] = v.w;
        }
        __syncthreads();
#pragma unroll 2
        for (int kk = 0; kk < 64; ++kk) {
            const float xv = xs[lane][kk];
            const float* __restrict__ Wrow = W + (c * 64 + kk) * 64 + cb;
#pragma unroll
            for (int j = 0; j < 32; ++j) acc[j] = fmaf(xv, Wrow[j], acc[j]);
        }
    }
    const int n = base + lane;
    float av = 0.f;
#pragma unroll
    for (int j = 0; j < 32; ++j) av = fmaf(att[cb + j], acc[j], av);
    if (K == 64) {
        // pre-summed single-float al for the L2 node pass
        if (w == 0) als[lane] = av;
        __syncthreads();
        if (w == 1 && n < N_NODES) alb[n] = als[lane] + av;
        if (blockIdx.x == 0 && t == 0) alb[SENT] = -1e30f;   // L2 sentinel
    } else {
        if (w < 2 && n < N_NODES) alb[(size_t)n * 2 + (w & 1)] = av;
    }
    if (n < N_NODES) {
        if (w < 2) {
            u32 pk[16];
#pragma unroll
            for (int j = 0; j < 32; j += 2) pk[j >> 1] = pack_bf16x2(acc[j], acc[j + 1]);
            uint4* dst = (uint4*)(xlb + (size_t)n * 32 + (w & 1) * 16);
#pragma unroll
            for (int j = 0; j < 4; ++j)
                dst[j] = make_uint4(pk[j * 4], pk[j * 4 + 1], pk[j * 4 + 2], pk[j * 4 + 3]);
        } else {
            arb[(size_t)n * 2 + (w & 1)] = av;
#pragma unroll
            for (int j = 0; j < 32; j += 4) {
                float4 v = {acc[j], acc[j + 1], acc[j + 2], acc[j + 3]};
                *(float4*)(xr + (size_t)n * 64 + cb + j) = v;
            }
        }
    }
}

// Expand: self-loop pre-seeded as entry 0; rows padded to x8 with SENT.
__global__ __launch_bounds__(256) void expand_kernel(
    const int* __restrict__ bucketBase, const int* __restrict__ sortedE,
    int* __restrict__ deg, int* __restrict__ rows) {
    __shared__ int ldeg[128];
    const int b = blockIdx.x;
    const int t = threadIdx.x;
    const int node_base = b * 128;
    if (t < 128) {
        const int n = node_base + t;
        ldeg[t] = 1;
        if (n < N_NODES) rows[(size_t)n * ROW_STRIDE] = n;   // self loop
    }
    __syncthreads();
    const int beg = bucketBase[b];
    const int end = bucketBase[b + 1];
    for (int i = beg + t; i < end; i += 256) {
        const int en = sortedE[i];
        const int ld = en & 127;
        const int pos = atomicAdd(&ldeg[ld], 1);
        if (pos < ROW_STRIDE) rows[(size_t)(node_base + ld) * ROW_STRIDE + pos] = en >> 7;
    }
    __syncthreads();
    if (t < 128) {
        const int n = node_base + t;
        if (n < N_NODES) {
            int c = ldeg[t];
            c = c < ROW_STRIDE ? c : ROW_STRIDE;
            const int cp = (c + 7) & ~7;
            for (int j = c; j < cp; ++j) rows[(size_t)n * ROW_STRIDE + j] = SENT;
            deg[n] = cp;
        }
    }
}

// ---------------------------------------------------------------------------
// Node-centric GATv2: one wave per dst node, 8 lanes/edge (8 bf16 ch/lane),
// 8 edges per wave-instruction. score = 0.6*(al_s + ar_d) + 0.4*sum att|u|.
// L1: al stride-2 (per head); L2: al pre-summed single float.
// ---------------------------------------------------------------------------
template <bool L1>
__global__ __launch_bounds__(256) void node_layer(
    const int* __restrict__ deg, const int* __restrict__ rows,
    const u32* __restrict__ xlb, const float* __restrict__ xr,
    const float* __restrict__ alb, const float* __restrict__ arb,
    const float* __restrict__ att, const float* __restrict__ bias,
    float* __restrict__ hout) {
    const int n = (blockIdx.x * 256 + threadIdx.x) >> 6;
    const int lane = threadIdx.x & 63;
    const int sub = lane & 7;        // channel octet: ch = sub*8 .. +7
    const int g = lane >> 3;         // edge slot 0..7
    const float4 xra = *(const float4*)(xr + (size_t)n * 64 + sub * 8);
    const float4 xrb = *(const float4*)(xr + (size_t)n * 64 + sub * 8 + 4);
    const float4 ata = *(const float4*)(att + sub * 8);
    const float4 atb = *(const float4*)(att + sub * 8 + 4);
    const float2 ar2 = *(const float2*)(arb + (size_t)n * 2);
    const float based = 0.6f * (L1 ? ((sub & 4) ? ar2.y : ar2.x) : (ar2.x + ar2.y));

    float c0 = 0.f, c1 = 0.f, c2 = 0.f, c3 = 0.f;
    float c4 = 0.f, c5 = 0.f, c6 = 0.f, c7 = 0.f;
    float ssum = 0.f;
    const int cp = __builtin_amdgcn_readfirstlane(deg[n]);
    const int* __restrict__ row = rows + (size_t)n * ROW_STRIDE;
    for (int i = 0; i < cp; i += 8) {
        const int s = row[i + g];
        const float als = L1 ? alb[(size_t)s * 2 + ((sub >> 2) & 1)] : alb[s];
        const uint4 r4 = *(const uint4*)(xlb + (size_t)s * 32 + sub * 4);
        const float a0 = bcf(r4.x << 16), a1 = bcf(r4.x & 0xFFFF0000u);
        const float a2f = bcf(r4.y << 16), a3 = bcf(r4.y & 0xFFFF0000u);
        const float a4 = bcf(r4.z << 16), a5 = bcf(r4.z & 0xFFFF0000u);
        const float a6 = bcf(r4.w << 16), a7 = bcf(r4.w & 0xFFFF0000u);
        float v = ata.x * fabsf(a0 + xra.x);
        v = fmaf(ata.y, fabsf(a1 + xra.y), v);
        v = fmaf(ata.z, fabsf(a2f + xra.z), v);
        v = fmaf(ata.w, fabsf(a3 + xra.w), v);
        v = fmaf(atb.x, fabsf(a4 + xrb.x), v);
        v = fmaf(atb.y, fabsf(a5 + xrb.y), v);
        v = fmaf(atb.z, fabsf(a6 + xrb.z), v);
        v = fmaf(atb.w, fabsf(a7 + xrb.w), v);
        v = dpp_add<0xB1>(v);            // xor 1
        v = dpp_add<0x4E>(v);            // xor 2  (L1: 4-lane head reduce done)
        if (!L1) v = dpp_add<0x141>(v);  // row_half_mirror: 8-lane reduce
        const float ev = __expf(fmaf(0.6f, als, fmaf(0.4f, v, based)));
        c0 = fmaf(ev, a0, c0); c1 = fmaf(ev, a1, c1);
        c2 = fmaf(ev, a2f, c2); c3 = fmaf(ev, a3, c3);
        c4 = fmaf(ev, a4, c4); c5 = fmaf(ev, a5, c5);
        c6 = fmaf(ev, a6, c6); c7 = fmaf(ev, a7, c7);
        ssum += ev;
    }
#define XRED(x) x += __shfl_xor(x, 8); x += __shfl_xor(x, 16); x += __shfl_xor(x, 32);
    XRED(c0) XRED(c1) XRED(c2) XRED(c3) XRED(c4) XRED(c5) XRED(c6) XRED(c7) XRED(ssum)
#undef XRED
    if (g == 0) {
        const float inv = 1.f / (ssum + 1e-16f);
        const float4 ba = *(const float4*)(bias + sub * 8);
        const float4 bb = *(const float4*)(bias + sub * 8 + 4);
        float o[8] = {c0 * inv + ba.x, c1 * inv + ba.y, c2 * inv + ba.z, c3 * inv + ba.w,
                      c4 * inv + bb.x, c5 * inv + bb.y, c6 * inv + bb.z, c7 * inv + bb.w};
#pragma unroll
        for (int j = 0; j < 8; ++j) o[j] = o[j] > 0.f ? o[j] : expm1f(o[j]);
        *(float4*)(hout + (size_t)n * 64 + sub * 8) = make_float4(o[0], o[1], o[2], o[3]);
        *(float4*)(hout + (size_t)n * 64 + sub * 8 + 4) = make_float4(o[4], o[5], o[6], o[7]);
    }
}

// Mean-pool accumulation over sorted batch ids.
__global__ __launch_bounds__(64) void pool_kernel(
    const float* __restrict__ h2, const int* __restrict__ batch,
    float* __restrict__ pooled, float* __restrict__ cnt) {
    const int t = threadIdx.x;
    const int base = blockIdx.x * 64;
    float local = 0.f, lc = 0.f;
    int cur = -1;
    for (int j = 0; j < 64; ++j) {
        const int n = base + j;
        if (n >= N_NODES) break;
        const int g = batch[n];
        if (g != cur) {
            if (cur >= 0) {
                unsafeAtomicAdd(&pooled[cur * 64 + t], local);
                if (t == 0) unsafeAtomicAdd(&cnt[cur], lc);
            }
            cur = g; local = 0.f; lc = 0.f;
        }
        local += h2[n * 64 + t];
        lc += 1.f;
    }
    if (cur >= 0) {
        unsafeAtomicAdd(&pooled[cur * 64 + t], local);
        if (t == 0) unsafeAtomicAdd(&cnt[cur], lc);
    }
}

__global__ __launch_bounds__(128) void head_kernel(
    const float* __restrict__ pooled, const float* __restrict__ cnt,
    const float* __restrict__ lin_w, const float* __restrict__ lin_b,
    float* __restrict__ out) {
    const int i = threadIdx.x;          // 0..127 -> (g, k)
    const int g = i >> 1, k = i & 1;
    float c = cnt[g];
    c = c > 1.f ? c : 1.f;
    float a = 0.f;
#pragma unroll
    for (int j = 0; j < 64; ++j) a = fmaf(pooled[g * 64 + j] / c, lin_w[j * 2 + k], a);
    out[i] = a + lin_b[k];
}

extern "C" void kernel_launch(void* const* d_in, const int* in_sizes, int n_in,
                              void* d_out, int out_size, void* d_ws, size_t ws_size,
                              hipStream_t stream) {
    const float* x     = (const float*)d_in[0];
    const int*   ei    = (const int*)d_in[1];
    const int*   batch = (const int*)d_in[2];
    const float* Wl1   = (const float*)d_in[3];
    const float* Wr1   = (const float*)d_in[4];
    const float* att1  = (const float*)d_in[5];
    const float* b1    = (const float*)d_in[6];
    const float* Wl2   = (const float*)d_in[7];
    const float* Wr2   = (const float*)d_in[8];
    const float* att2  = (const float*)d_in[9];
    const float* b2    = (const float*)d_in[10];
    const float* lin_w = (const float*)d_in[11];
    const float* lin_b = (const float*)d_in[12];

    float* ws = (float*)d_ws;
    u32*   xlb      = (u32*)ws;                    //  1,601,536 (50048*32 bf16 dwords)
    float* xr       = ws + 1601536;                //  3,200,000
    float* h1       = ws + 4801536;                //  3,200,000 (reused as h2)
    float* alb      = ws + 8001536;                //    100,096 (50048*2)
    float* arb      = ws + 8101632;                //    100,096
    int*   rows     = (int*)(ws + 8201728);        //  4,003,840 (50048*80)
    int*   deg      = (int*)(ws + 12205568);       //     50,048
    int*   countsRM = (int*)(ws + 12255616);       //    100,096 (256*391)
    int*   scanT    = (int*)(ws + 12355712);       //    100,096 (391*256)
    int*   totals   = (int*)(ws + 12455808);       //        512
    int*   bb       = (int*)(ws + 12456320);       //        512 (bucketBase)
    float* pooled   = ws + 12456832;               //      4,096  -- memset start
    float* cnt      = ws + 12460928;               //         64
    int*   sortedE  = (int*)(ws + 12460992);       //  1,600,000
    // total ~14.06M floats ~= 56 MB (ws is 256 MiB)

    hipMemsetAsync(pooled, 0, (size_t)(4096 + 64) * sizeof(float), stream);

    const int gblocks = (N_NODES + 63) / 64;   // 782

    // ---- build prologue: histogram + scans (independent of gemm inputs) ----
    count_kernel<<<NBLK, 256, 0, stream>>>(ei, countsRM);
    scan_bucket<<<NB, 256, 0, stream>>>(countsRM, scanT, totals);
    scan_total<<<1, 512, 0, stream>>>(totals, bb, alb);

    // ---- layer-1 gemm fused with radix scatter (scatter hides under gemm) ----
    gemm_tiled<128, true><<<gblocks + NBLK, 256, 0, stream>>>(
        x, Wl1, Wr1, att1, xlb, xr, alb, arb, ei, scanT, bb, sortedE, gblocks);

    expand_kernel<<<NB, 256, 0, stream>>>(bb, sortedE, deg, rows);

    // ---- layer 1 node pass ----
    node_layer<true><<<N_NODES / 4, 256, 0, stream>>>(
        deg, rows, xlb, xr, alb, arb, att1, b1, h1);

    // ---- layer 2 (h2 reuses h1 buffer; gemm consumed h1 first) ----
    gemm_tiled<64, false><<<gblocks, 256, 0, stream>>>(
        h1, Wl2, Wr2, att2, xlb, xr, alb, arb, nullptr, nullptr, nullptr, nullptr, gblocks);
    node_layer<false><<<N_NODES / 4, 256, 0, stream>>>(
        deg, rows, xlb, xr, alb, arb, att2, b2, h1);

    // ---- pool + head ----
    pool_kernel<<<(N_NODES + 63) / 64, 64, 0, stream>>>(h1, batch, pooled, cnt);
    head_kernel<<<1, 128, 0, stream>>>(pooled, cnt, lin_w, lin_b, (float*)d_out);
}

// Round 12
// 297.821 us; speedup vs baseline: 1.6102x; 1.0167x over previous
//
#include <hip/hip_runtime.h>
#include <hip/hip_bf16.h>
#include <math.h>

#define N_NODES 50000
#define N_EDGES 1600000
#define N_GRAPHS 64
#define NB 391             // dst buckets of 128 nodes: b = dst >> 7
#define NBLK 256           // partition blocks
#define CHUNK 6250         // edges per partition block (256*6250 = 1.6M exactly)
#define ROW_STRIDE 80      // per-node adjacency capacity (multiple of 8)
#define SENT 50047         // sentinel node: al[SENT] = -1e30 -> exp(score) = 0

typedef unsigned int u32;
typedef __attribute__((ext_vector_type(8))) __bf16 bf16x8;
typedef __attribute__((ext_vector_type(4))) float f32x4;

__device__ __forceinline__ float bcf(u32 u) { return __builtin_bit_cast(float, u); }

template <int CTRL>
__device__ __forceinline__ float dpp_add(float v) {
    int r = __builtin_amdgcn_update_dpp(0, __builtin_bit_cast(int, v), CTRL, 0xF, 0xF, true);
    return v + __builtin_bit_cast(float, r);
}

__device__ __forceinline__ u32 pack_bf16x2(float lo, float hi) {
    unsigned short l = __builtin_bit_cast(unsigned short, __float2bfloat16(lo));
    unsigned short h = __builtin_bit_cast(unsigned short, __float2bfloat16(hi));
    return (u32)l | ((u32)h << 16);
}

// ---------------------------------------------------------------------------
// W -> MFMA-B-fragment layout, hi/lo residual split.
// frag element i of (tile=ko*8+nt, lane L) = W[k=ko*32+(L>>4)*8+i][c=nt*16+(L&15)]
// combined cols: c<64 -> Wl, else Wr. One block.
// ---------------------------------------------------------------------------
template <int K>
__global__ __launch_bounds__(256) void conv_w(
    const float* __restrict__ Wl, const float* __restrict__ Wr,
    u32* __restrict__ wfHi, u32* __restrict__ wfLo) {
    const int KO = K / 32;
    for (int idx = threadIdx.x; idx < KO * 8 * 64; idx += 256) {
        const int L = idx & 63;
        const int tile = idx >> 6;
        const int ko = tile >> 3, nt = tile & 7;
        const int c = nt * 16 + (L & 15);
        u32 hi[4], lo[4];
        float hv[8], lv[8];
#pragma unroll
        for (int i = 0; i < 8; ++i) {
            const int k = ko * 32 + (L >> 4) * 8 + i;
            const float wv = (c < 64) ? Wl[k * 64 + c] : Wr[k * 64 + (c - 64)];
            const __hip_bfloat16 h = __float2bfloat16(wv);
            hv[i] = wv;
            lv[i] = wv - __bfloat162float(h);
        }
#pragma unroll
        for (int i = 0; i < 4; ++i) {
            hi[i] = pack_bf16x2(hv[2 * i], hv[2 * i + 1]);
            lo[i] = pack_bf16x2(lv[2 * i], lv[2 * i + 1]);
        }
        *(uint4*)(wfHi + (size_t)idx * 4) = make_uint4(hi[0], hi[1], hi[2], hi[3]);
        *(uint4*)(wfLo + (size_t)idx * 4) = make_uint4(lo[0], lo[1], lo[2], lo[3]);
    }
}

// ---------------------------------------------------------------------------
// x f32 -> packed bf16 rows; blocks >= convBlocks run the edge-bucket
// histogram (independent work fused to hide it).
// ---------------------------------------------------------------------------
__global__ __launch_bounds__(256) void conv_x_count(
    const float* __restrict__ x, u32* __restrict__ xbf,
    const int* __restrict__ ei, int* __restrict__ countsRM, int convBlocks) {
    __shared__ int h[NB];
    if (blockIdx.x >= convBlocks) {
        const int t = threadIdx.x;
        const int cb = blockIdx.x - convBlocks;
        for (int k = t; k < NB; k += 256) h[k] = 0;
        __syncthreads();
        const int base = cb * CHUNK;
        for (int e = base + t; e < base + CHUNK; e += 256)
            atomicAdd(&h[ei[N_EDGES + e] >> 7], 1);
        __syncthreads();
        for (int k = t; k < NB; k += 256) countsRM[cb * NB + k] = h[k];
        return;
    }
    const int units = N_NODES * 128 / 8;   // 8 floats per unit
    const int stride = convBlocks * 256;
    for (int u = blockIdx.x * 256 + threadIdx.x; u < units; u += stride) {
        const float4 a = *(const float4*)(x + (size_t)u * 8);
        const float4 b = *(const float4*)(x + (size_t)u * 8 + 4);
        *(uint4*)(xbf + (size_t)u * 4) = make_uint4(
            pack_bf16x2(a.x, a.y), pack_bf16x2(a.z, a.w),
            pack_bf16x2(b.x, b.y), pack_bf16x2(b.z, b.w));
    }
}

__global__ __launch_bounds__(256) void scan_bucket(
    const int* __restrict__ countsRM, int* __restrict__ scanT,
    int* __restrict__ totals) {
    __shared__ int tmp[256];
    const int b = blockIdx.x;
    const int t = threadIdx.x;
    const int v0 = countsRM[t * NB + b];
    tmp[t] = v0;
    __syncthreads();
    for (int off = 1; off < 256; off <<= 1) {
        int v = (t >= off) ? tmp[t - off] : 0;
        __syncthreads();
        tmp[t] += v;
        __syncthreads();
    }
    scanT[b * 256 + t] = tmp[t] - v0;   // exclusive
    if (t == 255) totals[b] = tmp[t];
}

__global__ __launch_bounds__(512) void scan_total(
    const int* __restrict__ totals, int* __restrict__ bucketBase,
    float* __restrict__ alb) {
    __shared__ int tmp[512];
    const int t = threadIdx.x;
    const int v0 = (t < NB) ? totals[t] : 0;
    tmp[t] = v0;
    __syncthreads();
    for (int off = 1; off < 512; off <<= 1) {
        int v = (t >= off) ? tmp[t - off] : 0;
        __syncthreads();
        tmp[t] += v;
        __syncthreads();
    }
    if (t < NB) bucketBase[t] = tmp[t] - v0;
    if (t == NB - 1) bucketBase[NB] = tmp[t];
    // L1-layout sentinel (indices 100094/100095; gemm writes only < 100000)
    if (t == 0) { alb[(size_t)SENT * 2] = -1e30f; alb[(size_t)SENT * 2 + 1] = -1e30f; }
}

// ---------------------------------------------------------------------------
// MFMA dense transform: [xl|xr] = x @ [Wl|Wr], via bf16 16x16x32 MFMA with
// W = Whi + Wlo residual (two passes, f32 acc -> W-rounding negligible).
// Block = 64 nodes (wave w -> m-tile w), 8 n-tiles (128 cols), K-loop.
// Epilogue through padded LDS tile: pack xl->bf16, xr->f32, att-dots al/ar.
// FUSE_SCATTER: blocks >= gemmBlocks run the radix scatter (LDS aliased).
// K==64 (layer 2): al written pre-summed; block 0 sets L2 sentinel.
// ---------------------------------------------------------------------------
template <int K, bool FUSE_SCATTER>
__global__ __launch_bounds__(256) void gemm_mfma(
    const u32* __restrict__ xbf, const u32* __restrict__ wfHi,
    const u32* __restrict__ wfLo, const float* __restrict__ att,
    u32* __restrict__ xlb, float* __restrict__ xr,
    float* __restrict__ alb, float* __restrict__ arb,
    const int* __restrict__ ei, const int* __restrict__ scanT,
    const int* __restrict__ bb, int* __restrict__ sortedE, int gemmBlocks) {
    __shared__ float Ct[64][129];   // +1 pad: column reads conflict-free
    __shared__ float alq[64][4];
    const int t = threadIdx.x;
    if (FUSE_SCATTER && blockIdx.x >= gemmBlocks) {
        int* cursor = (int*)&Ct[0][0];
        const int b = blockIdx.x - gemmBlocks;
        for (int k = t; k < NB; k += 256)
            cursor[k] = bb[k] + scanT[k * 256 + b];
        __syncthreads();
        const int base = b * CHUNK;
        for (int e = base + t; e < base + CHUNK; e += 256) {
            const int s = ei[e];
            const int d = ei[N_EDGES + e];
            const int idx = atomicAdd(&cursor[d >> 7], 1);   // LDS atomic
            sortedE[idx] = (s << 7) | (d & 127);
        }
        return;
    }
    const int KO = K / 32;
    const int lane = t & 63;
    const int w = __builtin_amdgcn_readfirstlane(t >> 6);
    const int quad = lane >> 4;
    const int m16 = lane & 15;
    const int base = blockIdx.x * 64;
    const int arow = base + w * 16 + m16;
    const u32* aptr = xbf + ((size_t)arow * K + quad * 8) / 2;   // dword index

    f32x4 acc[8];
    const f32x4 zz = {0.f, 0.f, 0.f, 0.f};
#pragma unroll
    for (int i = 0; i < 8; ++i) acc[i] = zz;

#pragma unroll
    for (int ko = 0; ko < KO; ++ko) {
        const uint4 au = *(const uint4*)(aptr + ko * 16);
        const bf16x8 af = __builtin_bit_cast(bf16x8, au);
#pragma unroll
        for (int nt = 0; nt < 8; ++nt) {
            const uint4 bh = *(const uint4*)(wfHi + (size_t)((ko * 8 + nt) * 64 + lane) * 4);
            acc[nt] = __builtin_amdgcn_mfma_f32_16x16x32_bf16(
                af, __builtin_bit_cast(bf16x8, bh), acc[nt], 0, 0, 0);
        }
#pragma unroll
        for (int nt = 0; nt < 8; ++nt) {
            const uint4 bl = *(const uint4*)(wfLo + (size_t)((ko * 8 + nt) * 64 + lane) * 4);
            acc[nt] = __builtin_amdgcn_mfma_f32_16x16x32_bf16(
                af, __builtin_bit_cast(bf16x8, bl), acc[nt], 0, 0, 0);
        }
    }
    // C/D layout: col = lane&15, row = quad*4 + reg   [verified mapping]
#pragma unroll
    for (int nt = 0; nt < 8; ++nt)
#pragma unroll
        for (int r = 0; r < 4; ++r)
            Ct[w * 16 + quad * 4 + r][nt * 16 + m16] = acc[nt][r];
    __syncthreads();

    const int node = t & 63;
    const int q = t >> 6;          // quarter: 0,1 -> xl cols; 2,3 -> xr cols
    const int n = base + node;
    float av = 0.f;
    if (n < N_NODES) {
        if (q < 2) {
            u32 pk[16];
#pragma unroll
            for (int j = 0; j < 32; j += 2) {
                const float v0 = Ct[node][q * 32 + j];
                const float v1 = Ct[node][q * 32 + j + 1];
                av = fmaf(att[q * 32 + j], v0, av);
                av = fmaf(att[q * 32 + j + 1], v1, av);
                pk[j >> 1] = pack_bf16x2(v0, v1);
            }
            uint4* dst = (uint4*)(xlb + (size_t)n * 32 + q * 16);
#pragma unroll
            for (int j = 0; j < 4; ++j)
                dst[j] = make_uint4(pk[j * 4], pk[j * 4 + 1], pk[j * 4 + 2], pk[j * 4 + 3]);
        } else {
            const int cb = (q - 2) * 32;
#pragma unroll
            for (int j = 0; j < 32; j += 4) {
                float4 v = {Ct[node][64 + cb + j], Ct[node][64 + cb + j + 1],
                            Ct[node][64 + cb + j + 2], Ct[node][64 + cb + j + 3]};
                av = fmaf(att[cb + j], v.x, av);
                av = fmaf(att[cb + j + 1], v.y, av);
                av = fmaf(att[cb + j + 2], v.z, av);
                av = fmaf(att[cb + j + 3], v.w, av);
                *(float4*)(xr + (size_t)n * 64 + cb + j) = v;
            }
        }
    }
    alq[node][q] = av;
    __syncthreads();
    if (t < 64 && base + t < N_NODES) {
        const int nn = base + t;
        if (K == 128) {
            alb[(size_t)nn * 2] = alq[t][0];
            alb[(size_t)nn * 2 + 1] = alq[t][1];
        } else {
            alb[nn] = alq[t][0] + alq[t][1];   // pre-summed for L2
        }
        arb[(size_t)nn * 2] = alq[t][2];
        arb[(size_t)nn * 2 + 1] = alq[t][3];
    }
    if (K == 64 && blockIdx.x == 0 && t == 0) alb[SENT] = -1e30f;   // L2 sentinel
}

// Expand: self-loop pre-seeded as entry 0; rows padded to x8 with SENT.
__global__ __launch_bounds__(256) void expand_kernel(
    const int* __restrict__ bucketBase, const int* __restrict__ sortedE,
    int* __restrict__ deg, int* __restrict__ rows) {
    __shared__ int ldeg[128];
    const int b = blockIdx.x;
    const int t = threadIdx.x;
    const int node_base = b * 128;
    if (t < 128) {
        const int n = node_base + t;
        ldeg[t] = 1;
        if (n < N_NODES) rows[(size_t)n * ROW_STRIDE] = n;   // self loop
    }
    __syncthreads();
    const int beg = bucketBase[b];
    const int end = bucketBase[b + 1];
    for (int i = beg + t; i < end; i += 256) {
        const int en = sortedE[i];
        const int ld = en & 127;
        const int pos = atomicAdd(&ldeg[ld], 1);
        if (pos < ROW_STRIDE) rows[(size_t)(node_base + ld) * ROW_STRIDE + pos] = en >> 7;
    }
    __syncthreads();
    if (t < 128) {
        const int n = node_base + t;
        if (n < N_NODES) {
            int c = ldeg[t];
            c = c < ROW_STRIDE ? c : ROW_STRIDE;
            const int cp = (c + 7) & ~7;
            for (int j = c; j < cp; ++j) rows[(size_t)n * ROW_STRIDE + j] = SENT;
            deg[n] = cp;
        }
    }
}

// ---------------------------------------------------------------------------
// Node-centric GATv2: one wave per dst node, 8 lanes/edge (8 bf16 ch/lane),
// 8 edges per wave-instruction. score = 0.6*(al_s + ar_d) + 0.4*sum att|u|.
// L1: al stride-2 per head; output packed bf16 (feeds gemm2's MFMA A).
// L2: al pre-summed; output f32 (feeds pool).
// ---------------------------------------------------------------------------
template <bool L1>
__global__ __launch_bounds__(256) void node_layer(
    const int* __restrict__ deg, const int* __restrict__ rows,
    const u32* __restrict__ xlb, const float* __restrict__ xr,
    const float* __restrict__ alb, const float* __restrict__ arb,
    const float* __restrict__ att, const float* __restrict__ bias,
    u32* __restrict__ houtB, float* __restrict__ houtF) {
    const int n = (blockIdx.x * 256 + threadIdx.x) >> 6;
    const int lane = threadIdx.x & 63;
    const int sub = lane & 7;        // channel octet: ch = sub*8 .. +7
    const int g = lane >> 3;         // edge slot 0..7
    const float4 xra = *(const float4*)(xr + (size_t)n * 64 + sub * 8);
    const float4 xrb = *(const float4*)(xr + (size_t)n * 64 + sub * 8 + 4);
    const float4 ata = *(const float4*)(att + sub * 8);
    const float4 atb = *(const float4*)(att + sub * 8 + 4);
    const float2 ar2 = *(const float2*)(arb + (size_t)n * 2);
    const float based = 0.6f * (L1 ? ((sub & 4) ? ar2.y : ar2.x) : (ar2.x + ar2.y));

    float c0 = 0.f, c1 = 0.f, c2 = 0.f, c3 = 0.f;
    float c4 = 0.f, c5 = 0.f, c6 = 0.f, c7 = 0.f;
    float ssum = 0.f;
    const int cp = __builtin_amdgcn_readfirstlane(deg[n]);
    const int* __restrict__ row = rows + (size_t)n * ROW_STRIDE;
    for (int i = 0; i < cp; i += 8) {
        const int s = row[i + g];
        const float als = L1 ? alb[(size_t)s * 2 + ((sub >> 2) & 1)] : alb[s];
        const uint4 r4 = *(const uint4*)(xlb + (size_t)s * 32 + sub * 4);
        const float a0 = bcf(r4.x << 16), a1 = bcf(r4.x & 0xFFFF0000u);
        const float a2f = bcf(r4.y << 16), a3 = bcf(r4.y & 0xFFFF0000u);
        const float a4 = bcf(r4.z << 16), a5 = bcf(r4.z & 0xFFFF0000u);
        const float a6 = bcf(r4.w << 16), a7 = bcf(r4.w & 0xFFFF0000u);
        float v = ata.x * fabsf(a0 + xra.x);
        v = fmaf(ata.y, fabsf(a1 + xra.y), v);
        v = fmaf(ata.z, fabsf(a2f + xra.z), v);
        v = fmaf(ata.w, fabsf(a3 + xra.w), v);
        v = fmaf(atb.x, fabsf(a4 + xrb.x), v);
        v = fmaf(atb.y, fabsf(a5 + xrb.y), v);
        v = fmaf(atb.z, fabsf(a6 + xrb.z), v);
        v = fmaf(atb.w, fabsf(a7 + xrb.w), v);
        v = dpp_add<0xB1>(v);            // xor 1
        v = dpp_add<0x4E>(v);            // xor 2  (L1: 4-lane head reduce done)
        if (!L1) v = dpp_add<0x141>(v);  // row_half_mirror: 8-lane reduce
        const float ev = __expf(fmaf(0.6f, als, fmaf(0.4f, v, based)));
        c0 = fmaf(ev, a0, c0); c1 = fmaf(ev, a1, c1);
        c2 = fmaf(ev, a2f, c2); c3 = fmaf(ev, a3, c3);
        c4 = fmaf(ev, a4, c4); c5 = fmaf(ev, a5, c5);
        c6 = fmaf(ev, a6, c6); c7 = fmaf(ev, a7, c7);
        ssum += ev;
    }
#define XRED(x) x += __shfl_xor(x, 8); x += __shfl_xor(x, 16); x += __shfl_xor(x, 32);
    XRED(c0) XRED(c1) XRED(c2) XRED(c3) XRED(c4) XRED(c5) XRED(c6) XRED(c7) XRED(ssum)
#undef XRED
    if (g == 0) {
        const float inv = 1.f / (ssum + 1e-16f);
        const float4 ba = *(const float4*)(bias + sub * 8);
        const float4 bb = *(const float4*)(bias + sub * 8 + 4);
        float o[8] = {c0 * inv + ba.x, c1 * inv + ba.y, c2 * inv + ba.z, c3 * inv + ba.w,
                      c4 * inv + bb.x, c5 * inv + bb.y, c6 * inv + bb.z, c7 * inv + bb.w};
#pragma unroll
        for (int j = 0; j < 8; ++j) o[j] = o[j] > 0.f ? o[j] : expm1f(o[j]);
        if (L1) {
            *(uint4*)(houtB + (size_t)n * 32 + sub * 4) = make_uint4(
                pack_bf16x2(o[0], o[1]), pack_bf16x2(o[2], o[3]),
                pack_bf16x2(o[4], o[5]), pack_bf16x2(o[6], o[7]));
        } else {
            *(float4*)(houtF + (size_t)n * 64 + sub * 8) = make_float4(o[0], o[1], o[2], o[3]);
            *(float4*)(houtF + (size_t)n * 64 + sub * 8 + 4) = make_float4(o[4], o[5], o[6], o[7]);
        }
    }
}

// Mean-pool accumulation over sorted batch ids.
__global__ __launch_bounds__(64) void pool_kernel(
    const float* __restrict__ h2, const int* __restrict__ batch,
    float* __restrict__ pooled, float* __restrict__ cnt) {
    const int t = threadIdx.x;
    const int base = blockIdx.x * 64;
    float local = 0.f, lc = 0.f;
    int cur = -1;
    for (int j = 0; j < 64; ++j) {
        const int n = base + j;
        if (n >= N_NODES) break;
        const int g = batch[n];
        if (g != cur) {
            if (cur >= 0) {
                unsafeAtomicAdd(&pooled[cur * 64 + t], local);
                if (t == 0) unsafeAtomicAdd(&cnt[cur], lc);
            }
            cur = g; local = 0.f; lc = 0.f;
        }
        local += h2[n * 64 + t];
        lc += 1.f;
    }
    if (cur >= 0) {
        unsafeAtomicAdd(&pooled[cur * 64 + t], local);
        if (t == 0) unsafeAtomicAdd(&cnt[cur], lc);
    }
}

__global__ __launch_bounds__(128) void head_kernel(
    const float* __restrict__ pooled, const float* __restrict__ cnt,
    const float* __restrict__ lin_w, const float* __restrict__ lin_b,
    float* __restrict__ out) {
    const int i = threadIdx.x;          // 0..127 -> (g, k)
    const int g = i >> 1, k = i & 1;
    float c = cnt[g];
    c = c > 1.f ? c : 1.f;
    float a = 0.f;
#pragma unroll
    for (int j = 0; j < 64; ++j) a = fmaf(pooled[g * 64 + j] / c, lin_w[j * 2 + k], a);
    out[i] = a + lin_b[k];
}

extern "C" void kernel_launch(void* const* d_in, const int* in_sizes, int n_in,
                              void* d_out, int out_size, void* d_ws, size_t ws_size,
                              hipStream_t stream) {
    const float* x     = (const float*)d_in[0];
    const int*   ei    = (const int*)d_in[1];
    const int*   batch = (const int*)d_in[2];
    const float* Wl1   = (const float*)d_in[3];
    const float* Wr1   = (const float*)d_in[4];
    const float* att1  = (const float*)d_in[5];
    const float* b1    = (const float*)d_in[6];
    const float* Wl2   = (const float*)d_in[7];
    const float* Wr2   = (const float*)d_in[8];
    const float* att2  = (const float*)d_in[9];
    const float* b2    = (const float*)d_in[10];
    const float* lin_w = (const float*)d_in[11];
    const float* lin_b = (const float*)d_in[12];

    float* ws = (float*)d_ws;     // offsets in dwords
    u32*   xbf      = (u32*)ws;                    //  3,203,072 (50048*64 dwords)
    u32*   h1b      = (u32*)(ws + 3203072);        //  1,601,536 (50048*32)
    u32*   xlb      = (u32*)(ws + 4804608);        //  1,601,536
    float* xr       = ws + 6406144;                //  3,203,072 (50048*64)
    float* h2       = ws + 9609216;                //  3,203,072
    float* alb      = ws + 12812288;               //    100,096
    float* arb      = ws + 12912384;               //    100,096
    int*   rows     = (int*)(ws + 13012480);       //  4,003,840 (50048*80)
    int*   deg      = (int*)(ws + 17016320);       //     50,048
    int*   countsRM = (int*)(ws + 17066368);       //    100,096 (256*391)
    int*   scanT    = (int*)(ws + 17166464);       //    100,096
    int*   totals   = (int*)(ws + 17266560);       //        512
    int*   bb       = (int*)(ws + 17267072);       //        512
    float* pooled   = ws + 17267584;               //      4,096  -- memset start
    float* cnt      = ws + 17271680;               //         64
    int*   sortedE  = (int*)(ws + 17271744);       //  1,600,000
    u32*   wf1hi    = (u32*)(ws + 18871744);       //      8,192
    u32*   wf1lo    = (u32*)(ws + 18879936);       //      8,192
    u32*   wf2hi    = (u32*)(ws + 18888128);       //      4,096
    u32*   wf2lo    = (u32*)(ws + 18892224);       //      4,096
    // total ~18.9M dwords ~= 75.6 MB (ws is 256 MiB)

    hipMemsetAsync(pooled, 0, (size_t)(4096 + 64) * sizeof(float), stream);

    const int gblocks = (N_NODES + 63) / 64;   // 782
    const int convBlocks = 512;

    // ---- weight fragments (tiny) + x->bf16 convert fused with histogram ----
    conv_w<128><<<1, 256, 0, stream>>>(Wl1, Wr1, wf1hi, wf1lo);
    conv_w<64><<<1, 256, 0, stream>>>(Wl2, Wr2, wf2hi, wf2lo);
    conv_x_count<<<convBlocks + NBLK, 256, 0, stream>>>(x, xbf, ei, countsRM, convBlocks);

    scan_bucket<<<NB, 256, 0, stream>>>(countsRM, scanT, totals);
    scan_total<<<1, 512, 0, stream>>>(totals, bb, alb);

    // ---- layer-1 MFMA gemm fused with radix scatter ----
    gemm_mfma<128, true><<<gblocks + NBLK, 256, 0, stream>>>(
        xbf, wf1hi, wf1lo, att1, xlb, xr, alb, arb, ei, scanT, bb, sortedE, gblocks);

    expand_kernel<<<NB, 256, 0, stream>>>(bb, sortedE, deg, rows);

    // ---- layer 1 node pass (emits packed bf16 h1) ----
    node_layer<true><<<N_NODES / 4, 256, 0, stream>>>(
        deg, rows, xlb, xr, alb, arb, att1, b1, h1b, nullptr);

    // ---- layer 2 ----
    gemm_mfma<64, false><<<gblocks, 256, 0, stream>>>(
        h1b, wf2hi, wf2lo, att2, xlb, xr, alb, arb, nullptr, nullptr, nullptr, nullptr, gblocks);
    node_layer<false><<<N_NODES / 4, 256, 0, stream>>>(
        deg, rows, xlb, xr, alb, arb, att2, b2, nullptr, h2);

    // ---- pool + head ----
    pool_kernel<<<(N_NODES + 63) / 64, 64, 0, stream>>>(h2, batch, pooled, cnt);
    head_kernel<<<1, 128, 0, stream>>>(pooled, cnt, lin_w, lin_b, (float*)d_out);
}